// Round 2
// baseline (5101.917 us; speedup 1.0000x reference)
//
#include <hip/hip_runtime.h>
#include <hip/hip_bf16.h>

typedef __attribute__((ext_vector_type(8))) __bf16 bf16x8;
typedef __attribute__((ext_vector_type(8))) short short8;
typedef __attribute__((ext_vector_type(4))) float floatx4;

__device__ __forceinline__ float b2f(unsigned short u) {
    union { unsigned int i; float f; } v; v.i = ((unsigned int)u) << 16; return v.f;
}
__device__ __forceinline__ unsigned short f2b(float f) {
    __hip_bfloat16 h = __float2bfloat16(f);
    return __builtin_bit_cast(unsigned short, h);
}
// load element i of an EXTERNAL input whose dtype is decided by the flag
__device__ __forceinline__ float ldf(const void* p, long i, bool isf32) {
    return isf32 ? ((const float*)p)[i] : b2f(((const unsigned short*)p)[i]);
}

// ---------------------------------------------------------------------------
// dtype detector: reads first 256 u32 words of x. True-f32 N(0,1) data has
// exponent fields ~117..129 ("sane"); bf16-pair data decodes to exponent
// fields near 0 or >=240 ("insane"). Writes flag (1 = inputs are f32).
// ---------------------------------------------------------------------------
__global__ void detect_dtype(const unsigned int* __restrict__ x, int* __restrict__ flag) {
    const int lane = threadIdx.x;
    int sane = 0;
    for (int i = lane; i < 256; i += 64) {
        const unsigned e = (x[i] >> 23) & 0xFF;
        sane += (e >= 100 && e <= 140) ? 1 : 0;
    }
#pragma unroll
    for (int m = 1; m < 64; m <<= 1) sane += __shfl_xor(sane, m, 64);
    if (lane == 0) *flag = (sane >= 128) ? 1 : 0;
}

// ---------------------------------------------------------------------------
// bf16-MFMA GEMM: C[M,N] = A[M,K] * B[N,K]^T. 64x64 tile, BK=32.
// aExt/bExt: operand is an external input (dtype per flag). cMode: 1 = write
// f32 always (internal pre buffers), 2 = write per flag (final output).
// ---------------------------------------------------------------------------
__global__ __launch_bounds__(256) void gemm_bt(
    const void* __restrict__ A, const void* __restrict__ B, void* __restrict__ C,
    int M, int N, int K, int aExt, int bExt, int cMode, const int* __restrict__ flag) {
    const bool f32 = (*flag != 0);
    const bool a32 = aExt && f32, b32 = bExt && f32;
    const bool c32 = (cMode == 1) || (cMode == 2 && f32);

    __shared__ unsigned short As[64][40];
    __shared__ unsigned short Bs[64][40];
    const int tid = threadIdx.x;
    const int bm = blockIdx.y * 64, bn = blockIdx.x * 64;
    const int wave = tid >> 6, lane = tid & 63;
    const int wm = (wave >> 1) * 32, wn = (wave & 1) * 32;
    const int fr = lane & 15;
    const int fq = lane >> 4;
    floatx4 acc[2][2] = {};

    const int sr = tid >> 2, sc = (tid & 3) * 8;
    const long arow = (long)(bm + sr) * K + sc;
    const long brow = (long)(bn + sr) * K + sc;

    for (int k0 = 0; k0 < K; k0 += 32) {
        short8 av, bv;
        if (a32) {
            const float* p = (const float*)A + arow + k0;
            floatx4 f0 = *(const floatx4*)p, f1 = *(const floatx4*)(p + 4);
            av[0] = (short)f2b(f0[0]); av[1] = (short)f2b(f0[1]);
            av[2] = (short)f2b(f0[2]); av[3] = (short)f2b(f0[3]);
            av[4] = (short)f2b(f1[0]); av[5] = (short)f2b(f1[1]);
            av[6] = (short)f2b(f1[2]); av[7] = (short)f2b(f1[3]);
        } else {
            av = *(const short8*)((const unsigned short*)A + arow + k0);
        }
        if (b32) {
            const float* p = (const float*)B + brow + k0;
            floatx4 f0 = *(const floatx4*)p, f1 = *(const floatx4*)(p + 4);
            bv[0] = (short)f2b(f0[0]); bv[1] = (short)f2b(f0[1]);
            bv[2] = (short)f2b(f0[2]); bv[3] = (short)f2b(f0[3]);
            bv[4] = (short)f2b(f1[0]); bv[5] = (short)f2b(f1[1]);
            bv[6] = (short)f2b(f1[2]); bv[7] = (short)f2b(f1[3]);
        } else {
            bv = *(const short8*)((const unsigned short*)B + brow + k0);
        }
        *(short8*)&As[sr][sc] = av;
        *(short8*)&Bs[sr][sc] = bv;
        __syncthreads();
        bf16x8 af[2], bfr[2];
#pragma unroll
        for (int i = 0; i < 2; i++) {
            af[i]  = __builtin_bit_cast(bf16x8, *(const short8*)&As[wm + i * 16 + fr][fq * 8]);
            bfr[i] = __builtin_bit_cast(bf16x8, *(const short8*)&Bs[wn + i * 16 + fr][fq * 8]);
        }
#pragma unroll
        for (int mi = 0; mi < 2; mi++)
#pragma unroll
            for (int ni = 0; ni < 2; ni++)
                acc[mi][ni] = __builtin_amdgcn_mfma_f32_16x16x32_bf16(
                    af[mi], bfr[ni], acc[mi][ni], 0, 0, 0);
        __syncthreads();
    }
#pragma unroll
    for (int mi = 0; mi < 2; mi++)
#pragma unroll
        for (int ni = 0; ni < 2; ni++)
#pragma unroll
            for (int r2 = 0; r2 < 4; r2++) {
                const int m = bm + wm + mi * 16 + fq * 4 + r2;
                const int n = bn + wn + ni * 16 + fr;
                const float val = acc[mi][ni][r2];
                const long ci = (long)m * N + n;
                if (c32) ((float*)C)[ci] = val;
                else ((unsigned short*)C)[ci] = f2b(val);
            }
}

// ---------------------------------------------------------------------------
// alpha/beta: sigmoid(W @ x_row). One block per (b,t); 32 outputs x 8 threads.
// ---------------------------------------------------------------------------
__global__ __launch_bounds__(256) void ab_proj(
    const void* __restrict__ x, const void* __restrict__ Wa,
    const void* __restrict__ Wb, float* __restrict__ alpha,
    float* __restrict__ beta, const int* __restrict__ flag) {
    const bool f32 = (*flag != 0);
    const long bt = blockIdx.x;
    const int tid = threadIdx.x;
    const int o = tid >> 3, r = tid & 7;
    const void* W = (o < 16) ? Wa : Wb;
    const long wbase = (long)((o < 16) ? o : (o - 16)) * 2048;
    const long xbase = bt * 2048;
    float acc = 0.f;
    const int i0 = r * 256;
    for (int i = i0; i < i0 + 256; i++)
        acc += ldf(W, wbase + i, f32) * ldf(x, xbase + i, f32);
    acc += __shfl_xor(acc, 1, 64);
    acc += __shfl_xor(acc, 2, 64);
    acc += __shfl_xor(acc, 4, 64);
    if (r == 0) {
        const float s = 1.f / (1.f + __expf(-acc));
        if (o < 16) alpha[bt * 16 + o] = s;
        else beta[bt * 16 + (o - 16)] = s;
    }
}

// ---------------------------------------------------------------------------
// causal depthwise conv K=4 + SiLU + per-head(128ch) L2-norm. C=2048.
// pre is internal f32; cw/cb external.
// ---------------------------------------------------------------------------
__global__ __launch_bounds__(256) void conv_silu_norm(
    const float* __restrict__ pre, const void* __restrict__ cw,
    const void* __restrict__ cb, unsigned short* __restrict__ out,
    const int* __restrict__ flag) {
    const bool f32 = (*flag != 0);
    const int bt = blockIdx.x;
    const int t = bt & 2047;
    const int tid = threadIdx.x;
    const int c0 = tid * 8;
    float y[8];
    float ss = 0.f;
#pragma unroll
    for (int j = 0; j < 8; j++) {
        const int c = c0 + j;
        float acc = ldf(cb, c, f32);
#pragma unroll
        for (int i = 0; i < 4; i++) {
            if (t - 3 + i >= 0)
                acc += ldf(cw, c * 4 + i, f32) * pre[(long)(bt - 3 + i) * 2048 + c];
        }
        const float s = acc / (1.f + __expf(-acc));
        y[j] = s;
        ss += s * s;
    }
#pragma unroll
    for (int m = 1; m < 16; m <<= 1) ss += __shfl_xor(ss, m, 64);
    const float inv = rsqrtf(ss + 1e-12f);
#pragma unroll
    for (int j = 0; j < 8; j++) out[(long)bt * 2048 + c0 + j] = f2b(y[j] * inv);
}

// Same, no norm, C=4096 (v path).
__global__ __launch_bounds__(256) void conv_silu_v(
    const float* __restrict__ pre, const void* __restrict__ cw,
    const void* __restrict__ cb, unsigned short* __restrict__ out,
    const int* __restrict__ flag) {
    const bool f32 = (*flag != 0);
    const int bt = blockIdx.x;
    const int t = bt & 2047;
    const int tid = threadIdx.x;
    const int c0 = tid * 16;
#pragma unroll
    for (int j = 0; j < 16; j++) {
        const int c = c0 + j;
        float acc = ldf(cb, c, f32);
#pragma unroll
        for (int i = 0; i < 4; i++) {
            if (t - 3 + i >= 0)
                acc += ldf(cw, c * 4 + i, f32) * pre[(long)(bt - 3 + i) * 4096 + c];
        }
        out[(long)bt * 4096 + c] = f2b(acc / (1.f + __expf(-acc)));
    }
}

// ---------------------------------------------------------------------------
// Gated delta-rule recurrence. 256 blocks = (b,h,vb); block owns a 128x32
// state slice, fully independent. 256 threads: tid = kg*32+vl; thread owns
// S[kg*16+j][vl] in registers. 3 barriers/step (race-free: see analysis).
// ---------------------------------------------------------------------------
__global__ __launch_bounds__(256) void recurrence_kernel(
    const unsigned short* __restrict__ q, const unsigned short* __restrict__ k,
    const unsigned short* __restrict__ v, const float* __restrict__ alpha,
    const float* __restrict__ beta, const void* __restrict__ state_in,
    unsigned short* __restrict__ outs, void* __restrict__ d_out,
    int T, const int* __restrict__ flag) {
    const bool f32 = (*flag != 0);
    const int blk = blockIdx.x;
    const int vb = blk & 7, h = (blk >> 3) & 15, b = blk >> 7;
    const int tid = threadIdx.x;
    const int vl = tid & 31, kg = tid >> 5;
    const int vglob = vb * 32 + vl;

    float S[16];
    const long stbase = (((long)(b * 16 + h)) * 128 + kg * 16) * 256 + vglob;
#pragma unroll
    for (int j = 0; j < 16; j++) S[j] = ldf(state_in, stbase + (long)j * 256, f32);

    __shared__ float ldsK[128], ldsQ[128], ldsV[32], ldsA[2];
    __shared__ float pr[8][32], po[8][32];

    for (int t = 0; t < T; t++) {
        const long bt = (long)b * T + t;
        if (tid < 128) ldsK[tid] = b2f(k[bt * 2048 + h * 128 + tid]);
        else ldsQ[tid - 128] = b2f(q[bt * 2048 + h * 128 + (tid - 128)]);
        if (tid < 32) ldsV[tid] = b2f(v[bt * 4096 + h * 256 + vb * 32 + tid]);
        if (tid == 32) ldsA[0] = alpha[bt * 16 + h];
        if (tid == 33) ldsA[1] = beta[bt * 16 + h];
        __syncthreads();  // B1

        float kv[16];
#pragma unroll
        for (int j = 0; j < 16; j++) kv[j] = ldsK[kg * 16 + j];
        float prt = 0.f;
#pragma unroll
        for (int j = 0; j < 16; j++) prt += S[j] * kv[j];
        pr[kg][vl] = prt;
        __syncthreads();  // B2

        float r = 0.f;
#pragma unroll
        for (int g = 0; g < 8; g++) r += pr[g][vl];
        const float a = ldsA[0], bb = ldsA[1];
        const float err = ldsV[vl] - a * r;
        const float cc = bb * err;
        float pot = 0.f;
#pragma unroll
        for (int j = 0; j < 16; j++) {
            S[j] = a * S[j] + cc * kv[j];
            pot += S[j] * ldsQ[kg * 16 + j];
        }
        po[kg][vl] = pot;
        __syncthreads();  // B3

        if (kg == 0) {
            float o = 0.f;
#pragma unroll
            for (int g = 0; g < 8; g++) o += po[g][vl];
            outs[bt * 4096 + h * 256 + vglob] = f2b(o);
        }
        // writes at t+1 phase-1 only touch LDS read strictly before B3 here;
        // po readers finish before reaching B1(t+1) -> 3 barriers suffice.
    }
    // state output lives at element offset 8388608 (= B*T*H) in d_out
#pragma unroll
    for (int j = 0; j < 16; j++) {
        const long idx = 8388608L + stbase + (long)j * 256;
        if (f32) ((float*)d_out)[idx] = S[j];
        else ((unsigned short*)d_out)[idx] = f2b(S[j]);
    }
}

// ---------------------------------------------------------------------------
extern "C" void kernel_launch(void* const* d_in, const int* in_sizes, int n_in,
                              void* d_out, int out_size, void* d_ws, size_t ws_size,
                              hipStream_t stream) {
    const void* x   = d_in[0];
    const void* st0 = d_in[1];
    const void* Wq  = d_in[2];
    const void* Wk  = d_in[3];
    const void* Wv  = d_in[4];
    const void* Wo  = d_in[5];
    const void* Wa  = d_in[6];
    const void* Wb  = d_in[7];
    const void* qcW = d_in[8];
    const void* qcB = d_in[9];
    const void* kcW = d_in[10];
    const void* kcB = d_in[11];
    const void* vcW = d_in[12];
    const void* vcB = d_in[13];

    const int T = 2048, H = 2048, M = 4096;  // M = B*T

    // workspace layout: flag (256 B) then ~224.5 MiB of buffers
    int* flag = (int*)d_ws;
    float* qpre  = (float*)((char*)d_ws + 256);        // [4096,2048] f32
    float* kpre  = qpre + (size_t)M * 2048;
    float* vpre  = kpre + (size_t)M * 2048;            // [4096,4096] f32
    float* alpha = vpre + (size_t)M * 4096;            // [4096,16] f32
    float* beta  = alpha + (size_t)M * 16;
    unsigned short* qn   = (unsigned short*)(beta + (size_t)M * 16);  // bf16
    unsigned short* kn   = qn + (size_t)M * 2048;
    unsigned short* vn   = kn + (size_t)M * 2048;
    unsigned short* outs = vn + (size_t)M * 4096;

    dim3 blk(256);
    detect_dtype<<<dim3(1), dim3(64), 0, stream>>>((const unsigned int*)x, flag);

    gemm_bt<<<dim3(2048 / 64, M / 64), blk, 0, stream>>>(x, Wq, qpre, M, 2048, H, 1, 1, 1, flag);
    gemm_bt<<<dim3(2048 / 64, M / 64), blk, 0, stream>>>(x, Wk, kpre, M, 2048, H, 1, 1, 1, flag);
    gemm_bt<<<dim3(4096 / 64, M / 64), blk, 0, stream>>>(x, Wv, vpre, M, 4096, H, 1, 1, 1, flag);
    ab_proj<<<dim3(M), blk, 0, stream>>>(x, Wa, Wb, alpha, beta, flag);
    conv_silu_norm<<<dim3(M), blk, 0, stream>>>(qpre, qcW, qcB, qn, flag);
    conv_silu_norm<<<dim3(M), blk, 0, stream>>>(kpre, kcW, kcB, kn, flag);
    conv_silu_v<<<dim3(M), blk, 0, stream>>>(vpre, vcW, vcB, vn, flag);

    recurrence_kernel<<<dim3(256), blk, 0, stream>>>(qn, kn, vn, alpha, beta, st0,
                                                     outs, d_out, T, flag);
    // out = outs @ Wo^T  -> first 8388608 elements of d_out
    gemm_bt<<<dim3(2048 / 64, M / 64), blk, 0, stream>>>(
        outs, Wo, d_out, M, 2048, 4096, 0, 1, 2, flag);
}

// Round 3
// 2938.687 us; speedup vs baseline: 1.7361x; 1.7361x over previous
//
#include <hip/hip_runtime.h>
#include <hip/hip_bf16.h>

typedef __attribute__((ext_vector_type(8))) __bf16 bf16x8;
typedef __attribute__((ext_vector_type(8))) short short8;
typedef __attribute__((ext_vector_type(4))) float floatx4;
using u16 = unsigned short;

#define GLOBAL_AS __attribute__((address_space(1)))
#define LDS_AS    __attribute__((address_space(3)))

__device__ __forceinline__ float b2f(u16 u) {
    union { unsigned int i; float f; } v; v.i = ((unsigned int)u) << 16; return v.f;
}
__device__ __forceinline__ u16 f2b(float f) {
    __hip_bfloat16 h = __float2bfloat16(f);
    return __builtin_bit_cast(u16, h);
}
__device__ __forceinline__ float ldf(const void* p, long i, bool isf32) {
    return isf32 ? ((const float*)p)[i] : b2f(((const u16*)p)[i]);
}
// async global->LDS, 16B per lane; lds base must be wave-uniform
__device__ __forceinline__ void gload_lds16(const void* g, void* l) {
    __builtin_amdgcn_global_load_lds((const GLOBAL_AS unsigned int*)g,
                                     (LDS_AS unsigned int*)l, 16, 0, 0);
}
// sum over the 8 consecutive lanes of a kg-group, result in all 8 lanes (VALU DPP)
__device__ __forceinline__ float dpp_add(float x, int yi_as_int) { return x; }
__device__ __forceinline__ float red8(float x) {
    int xi, yi;
    xi = __builtin_bit_cast(int, x);
    yi = __builtin_amdgcn_update_dpp(xi, xi, 0xB1, 0xF, 0xF, false);   // quad_perm [1,0,3,2]
    x += __builtin_bit_cast(float, yi);
    xi = __builtin_bit_cast(int, x);
    yi = __builtin_amdgcn_update_dpp(xi, xi, 0x4E, 0xF, 0xF, false);   // quad_perm [2,3,0,1]
    x += __builtin_bit_cast(float, yi);
    xi = __builtin_bit_cast(int, x);
    yi = __builtin_amdgcn_update_dpp(xi, xi, 0x141, 0xF, 0xF, false);  // row_half_mirror
    x += __builtin_bit_cast(float, yi);
    return x;
}
__device__ __forceinline__ void unpack2(int d, float& lo, float& hi) {
    lo = __builtin_bit_cast(float, (int)((unsigned)d << 16));
    hi = __builtin_bit_cast(float, d & 0xffff0000);
}
__device__ __forceinline__ void unpack8(int4 d, float* f) {
    unpack2(d.x, f[0], f[1]); unpack2(d.y, f[2], f[3]);
    unpack2(d.z, f[4], f[5]); unpack2(d.w, f[6], f[7]);
}

// ---------------------------------------------------------------------------
// dtype detector (1 = inputs are f32)
// ---------------------------------------------------------------------------
__global__ void detect_dtype(const unsigned int* __restrict__ x, int* __restrict__ flag) {
    const int lane = threadIdx.x;
    int sane = 0;
    for (int i = lane; i < 256; i += 64) {
        const unsigned e = (x[i] >> 23) & 0xFF;
        sane += (e >= 100 && e <= 140) ? 1 : 0;
    }
#pragma unroll
    for (int m = 1; m < 64; m <<= 1) sane += __shfl_xor(sane, m, 64);
    if (lane == 0) *flag = (sane >= 128) ? 1 : 0;
}

// ---------------------------------------------------------------------------
// convert external tensor (f32 or bf16 per flag) -> bf16 buffer. n % 2048 == 0
// ---------------------------------------------------------------------------
__global__ __launch_bounds__(256) void cvt_bf16(
    const void* __restrict__ in, u16* __restrict__ out, long n, const int* __restrict__ flag) {
    const bool f32 = (*flag != 0);
    const long i = ((long)blockIdx.x * 256 + threadIdx.x) * 8;
    if (i >= n) return;
    if (f32) {
        const float* p = (const float*)in + i;
        floatx4 a = *(const floatx4*)p, b = *(const floatx4*)(p + 4);
        short8 o;
        o[0] = (short)f2b(a[0]); o[1] = (short)f2b(a[1]);
        o[2] = (short)f2b(a[2]); o[3] = (short)f2b(a[3]);
        o[4] = (short)f2b(b[0]); o[5] = (short)f2b(b[1]);
        o[6] = (short)f2b(b[2]); o[7] = (short)f2b(b[3]);
        *(short8*)(out + i) = o;
    } else {
        *(int4*)(out + i) = *(const int4*)((const u16*)in + i);
    }
}

// ---------------------------------------------------------------------------
// m97-class GEMM: C[M,N] = A[M,K] * B[N,K]^T, A/B bf16 row-major.
// 128x128 tile, BK=32, global_load_lds(16B), 4 waves x (4x4) 16x16x32 MFMA.
// cmode: 1 = f32 C, 3 = bf16 C, 2 = per-flag (f32 if flag else bf16)
// ---------------------------------------------------------------------------
__global__ __launch_bounds__(256) void gemm_bt128(
    const u16* __restrict__ A, const u16* __restrict__ B, void* __restrict__ C,
    int M, int N, int K, int cmode, const int* __restrict__ flag) {
    const bool c32 = (cmode == 1) || (cmode == 2 && *flag != 0);
    __shared__ __align__(16) u16 As[128 * 32];
    __shared__ __align__(16) u16 Bs[128 * 32];
    const int tid = threadIdx.x, lane = tid & 63, wave = tid >> 6;
    const int bm = blockIdx.y * 128, bn = blockIdx.x * 128;
    const int wm = (wave >> 1) * 64, wn = (wave & 1) * 64;
    const int fr = lane & 15, fq = lane >> 4;
    floatx4 acc[4][4] = {};

    const int srow = tid >> 2, scol = (tid & 3) * 8;       // 64 rows per call
    const long abase = (long)(bm + srow) * K + scol;
    const long bbase = (long)(bn + srow) * K + scol;
    char* lA = (char*)As + (tid & ~63) * 16;
    char* lB = (char*)Bs + (tid & ~63) * 16;

    for (int k0 = 0; k0 < K; k0 += 32) {
        __syncthreads();
        gload_lds16(A + abase + k0, lA);
        gload_lds16(A + abase + (long)64 * K + k0, lA + 4096);
        gload_lds16(B + bbase + k0, lB);
        gload_lds16(B + bbase + (long)64 * K + k0, lB + 4096);
        __syncthreads();
        bf16x8 af[4], bf[4];
#pragma unroll
        for (int i = 0; i < 4; i++) {
            af[i] = __builtin_bit_cast(bf16x8, *(const short8*)&As[(wm + i * 16 + fr) * 32 + fq * 8]);
            bf[i] = __builtin_bit_cast(bf16x8, *(const short8*)&Bs[(wn + i * 16 + fr) * 32 + fq * 8]);
        }
#pragma unroll
        for (int mi = 0; mi < 4; mi++)
#pragma unroll
            for (int ni = 0; ni < 4; ni++)
                acc[mi][ni] = __builtin_amdgcn_mfma_f32_16x16x32_bf16(
                    af[mi], bf[ni], acc[mi][ni], 0, 0, 0);
    }
#pragma unroll
    for (int mi = 0; mi < 4; mi++)
#pragma unroll
        for (int ni = 0; ni < 4; ni++)
#pragma unroll
            for (int r = 0; r < 4; r++) {
                const int m = bm + wm + mi * 16 + fq * 4 + r;
                const int n = bn + wn + ni * 16 + fr;
                const float val = acc[mi][ni][r];
                const long ci = (long)m * N + n;
                if (c32) ((float*)C)[ci] = val;
                else ((u16*)C)[ci] = f2b(val);
            }
}

// ---------------------------------------------------------------------------
// alpha/beta: sigmoid(W @ x_row) -> TRANSPOSED layouts [b*16+h][T]
// ---------------------------------------------------------------------------
__global__ __launch_bounds__(256) void ab_proj(
    const void* __restrict__ x, const void* __restrict__ Wa,
    const void* __restrict__ Wb, float* __restrict__ alphaT,
    float* __restrict__ betaT, const int* __restrict__ flag) {
    const bool f32 = (*flag != 0);
    const long bt = blockIdx.x;
    const int b = (int)(bt >> 11), t = (int)(bt & 2047);
    const int tid = threadIdx.x;
    const int o = tid >> 3, r = tid & 7;
    const void* W = (o < 16) ? Wa : Wb;
    const long wbase = (long)((o < 16) ? o : (o - 16)) * 2048;
    const long xbase = bt * 2048;
    float acc = 0.f;
    const int i0 = r * 256;
    for (int i = i0; i < i0 + 256; i++)
        acc += ldf(W, wbase + i, f32) * ldf(x, xbase + i, f32);
    acc += __shfl_xor(acc, 1, 64);
    acc += __shfl_xor(acc, 2, 64);
    acc += __shfl_xor(acc, 4, 64);
    if (r == 0) {
        const float s = 1.f / (1.f + __expf(-acc));
        const int oo = (o < 16) ? o : (o - 16);
        float* dst = (o < 16) ? alphaT : betaT;
        dst[((long)b * 16 + oo) * 2048 + t] = s;
    }
}

// ---------------------------------------------------------------------------
// causal depthwise conv K=4 + SiLU + per-head(128) L2 norm. pre is bf16.
// ---------------------------------------------------------------------------
__global__ __launch_bounds__(256) void conv_silu_norm(
    const u16* __restrict__ pre, const void* __restrict__ cw,
    const void* __restrict__ cb, u16* __restrict__ out, const int* __restrict__ flag) {
    const bool f32 = (*flag != 0);
    const int bt = blockIdx.x;
    const int t = bt & 2047;
    const int tid = threadIdx.x;
    const int c0 = tid * 8;
    float y[8];
    float ss = 0.f;
#pragma unroll
    for (int j = 0; j < 8; j++) {
        const int c = c0 + j;
        float acc = ldf(cb, c, f32);
#pragma unroll
        for (int i = 0; i < 4; i++) {
            if (t - 3 + i >= 0)
                acc += ldf(cw, c * 4 + i, f32) * b2f(pre[(long)(bt - 3 + i) * 2048 + c]);
        }
        const float s = acc / (1.f + __expf(-acc));
        y[j] = s;
        ss += s * s;
    }
#pragma unroll
    for (int m = 1; m < 16; m <<= 1) ss += __shfl_xor(ss, m, 64);
    const float inv = rsqrtf(ss + 1e-12f);
#pragma unroll
    for (int j = 0; j < 8; j++) out[(long)bt * 2048 + c0 + j] = f2b(y[j] * inv);
}

__global__ __launch_bounds__(256) void conv_silu_v(
    const u16* __restrict__ pre, const void* __restrict__ cw,
    const void* __restrict__ cb, u16* __restrict__ out, const int* __restrict__ flag) {
    const bool f32 = (*flag != 0);
    const int bt = blockIdx.x;
    const int t = bt & 2047;
    const int tid = threadIdx.x;
    const int c0 = tid * 16;
#pragma unroll
    for (int j = 0; j < 16; j++) {
        const int c = c0 + j;
        float acc = ldf(cb, c, f32);
#pragma unroll
        for (int i = 0; i < 4; i++) {
            if (t - 3 + i >= 0)
                acc += ldf(cw, c * 4 + i, f32) * b2f(pre[(long)(bt - 3 + i) * 4096 + c]);
        }
        out[(long)bt * 4096 + c] = f2b(acc / (1.f + __expf(-acc)));
    }
}

// ---------------------------------------------------------------------------
// Gated delta-rule recurrence, barrier-free steps.
// 256 blocks = (b,h,vb). 4 waves; wave owns 8 v-columns, full k (128).
// lane = vq*8+kg; lane owns S[kg*16+j][v], j=0..15. k-reduction = DPP over
// 8 consecutive lanes. k/q/v staged per 16-step chunk via global_load_lds.
// alpha/beta read as wave-uniform scalar loads from transposed buffers.
// ---------------------------------------------------------------------------
__global__ __launch_bounds__(256) void recurrence_kernel(
    const u16* __restrict__ qn, const u16* __restrict__ kn,
    const u16* __restrict__ vn, const float* __restrict__ alphaT,
    const float* __restrict__ betaT, const void* __restrict__ state_in,
    u16* __restrict__ outs, void* __restrict__ d_out, const int* __restrict__ flag) {
    const bool f32 = (*flag != 0);
    const int blk = blockIdx.x;
    const int vb = blk & 7, h = (blk >> 3) & 15, b = blk >> 7;
    const int tid = threadIdx.x, lane = tid & 63, wave = tid >> 6;
    const int kg = lane & 7, vq = lane >> 3;
    const int vloc = wave * 8 + vq;          // 0..31
    const int vglob = vb * 32 + vloc;

    float S[16];
    const long stbase = ((long)(b * 16 + h) * 128 + kg * 16) * 256 + vglob;
#pragma unroll
    for (int j = 0; j < 16; j++) S[j] = ldf(state_in, stbase + (long)j * 256, f32);

    __shared__ __align__(16) u16 kbuf[16 * 128];
    __shared__ __align__(16) u16 qbuf[16 * 128];
    __shared__ __align__(16) u16 vbuf[16 * 32];

    const long abase = (long)(b * 16 + h) * 2048;
    const int srow = tid >> 4, scol = (tid & 15) * 8;  // staging: 16 rows x 128
    char* lK = (char*)kbuf + (tid & ~63) * 16;
    char* lQ = (char*)qbuf + (tid & ~63) * 16;

    for (int c = 0; c < 128; ++c) {
        const int t0 = c * 16;
        __syncthreads();  // all waves done reading previous chunk
        const long gkq = ((long)b * 2048 + t0 + srow) * 2048 + h * 128 + scol;
        gload_lds16(kn + gkq, lK);
        gload_lds16(qn + gkq, lQ);
        if (tid < 64) {
            const long gv = ((long)b * 2048 + t0 + (lane >> 2)) * 4096 + h * 256 + vb * 32 + (lane & 3) * 8;
            gload_lds16(vn + gv, (char*)vbuf);
        }
        __syncthreads();  // staging complete (drains vmcnt)

#pragma unroll
        for (int tt = 0; tt < 16; ++tt) {
            const float a  = alphaT[abase + t0 + tt];
            const float bb = betaT[abase + t0 + tt];
            float kf[16], qf[16];
            unpack8(*(const int4*)(kbuf + tt * 128 + kg * 16), kf);
            unpack8(*(const int4*)(kbuf + tt * 128 + kg * 16 + 8), kf + 8);
            unpack8(*(const int4*)(qbuf + tt * 128 + kg * 16), qf);
            unpack8(*(const int4*)(qbuf + tt * 128 + kg * 16 + 8), qf + 8);
            float r0 = 0.f, r1 = 0.f;
#pragma unroll
            for (int j = 0; j < 8; j++) {
                r0 = fmaf(S[j], kf[j], r0);
                r1 = fmaf(S[8 + j], kf[8 + j], r1);
            }
            float r = red8(r0 + r1);
            const float vv = b2f(vbuf[tt * 32 + vloc]);
            const float err = fmaf(-a, r, vv);
            const float cc = bb * err;
            float o0 = 0.f, o1 = 0.f;
#pragma unroll
            for (int j = 0; j < 8; j++) {
                S[j] = fmaf(cc, kf[j], a * S[j]);
                S[8 + j] = fmaf(cc, kf[8 + j], a * S[8 + j]);
                o0 = fmaf(S[j], qf[j], o0);
                o1 = fmaf(S[8 + j], qf[8 + j], o1);
            }
            const float o = red8(o0 + o1);
            if (kg == 0)
                outs[((long)b * 2048 + t0 + tt) * 4096 + h * 256 + vglob] = f2b(o);
        }
    }
    // final state -> d_out at element offset B*T*H = 8388608
#pragma unroll
    for (int j = 0; j < 16; j++) {
        const long idx = 8388608L + stbase + (long)j * 256;
        if (f32) ((float*)d_out)[idx] = S[j];
        else ((u16*)d_out)[idx] = f2b(S[j]);
    }
}

// ---------------------------------------------------------------------------
extern "C" void kernel_launch(void* const* d_in, const int* in_sizes, int n_in,
                              void* d_out, int out_size, void* d_ws, size_t ws_size,
                              hipStream_t stream) {
    const void* x   = d_in[0];
    const void* st0 = d_in[1];
    const void* Wq  = d_in[2];
    const void* Wk  = d_in[3];
    const void* Wv  = d_in[4];
    const void* Wo  = d_in[5];
    const void* Wa  = d_in[6];
    const void* Wb  = d_in[7];
    const void* qcW = d_in[8];
    const void* qcB = d_in[9];
    const void* kcW = d_in[10];
    const void* kcB = d_in[11];
    const void* vcW = d_in[12];
    const void* vcB = d_in[13];

    const int M = 4096;  // B*T
    const long MB = 1024L * 1024L;
    char* w = (char*)d_ws;
    int*   flag   = (int*)w;                       // @0, 1KB pad
    float* alphaT = (float*)(w + 1024);            // 256 KB
    float* betaT  = (float*)(w + 1024 + 262144);   // 256 KB
    u16* xb    = (u16*)(w + 1 * MB);               // 16 MB  (reused for Wo later)
    u16* wqb   = (u16*)(w + 17 * MB);              // 8 MB
    u16* wkb   = (u16*)(w + 25 * MB);              // 8 MB
    u16* wvb   = (u16*)(w + 33 * MB);              // 16 MB
    u16* qpreb = (u16*)(w + 49 * MB);              // 16 MB
    u16* kpreb = (u16*)(w + 65 * MB);              // 16 MB
    u16* vpreb = (u16*)(w + 81 * MB);              // 32 MB
    u16* qn    = (u16*)(w + 113 * MB);             // 16 MB
    u16* kn    = (u16*)(w + 129 * MB);             // 16 MB
    u16* vn    = (u16*)(w + 145 * MB);             // 32 MB (ends 177 MB)
    u16* wob   = xb;                               // alias: x dead after proj GEMMs
    u16* outs  = qpreb;                            // alias: 32 MB (qpreb+kpreb)

    dim3 blk(256);
    detect_dtype<<<dim3(1), dim3(64), 0, stream>>>((const unsigned int*)x, flag);

    cvt_bf16<<<dim3(4096), blk, 0, stream>>>(x,  xb,  8388608L, flag);
    cvt_bf16<<<dim3(2048), blk, 0, stream>>>(Wq, wqb, 4194304L, flag);
    cvt_bf16<<<dim3(2048), blk, 0, stream>>>(Wk, wkb, 4194304L, flag);
    cvt_bf16<<<dim3(4096), blk, 0, stream>>>(Wv, wvb, 8388608L, flag);

    gemm_bt128<<<dim3(2048 / 128, M / 128), blk, 0, stream>>>(xb, wqb, qpreb, M, 2048, 2048, 3, flag);
    gemm_bt128<<<dim3(2048 / 128, M / 128), blk, 0, stream>>>(xb, wkb, kpreb, M, 2048, 2048, 3, flag);
    gemm_bt128<<<dim3(4096 / 128, M / 128), blk, 0, stream>>>(xb, wvb, vpreb, M, 4096, 2048, 3, flag);

    cvt_bf16<<<dim3(4096), blk, 0, stream>>>(Wo, wob, 8388608L, flag);  // after x readers

    ab_proj<<<dim3(M), blk, 0, stream>>>(x, Wa, Wb, alphaT, betaT, flag);
    conv_silu_norm<<<dim3(M), blk, 0, stream>>>(qpreb, qcW, qcB, qn, flag);
    conv_silu_norm<<<dim3(M), blk, 0, stream>>>(kpreb, kcW, kcB, kn, flag);
    conv_silu_v<<<dim3(M), blk, 0, stream>>>(vpreb, vcW, vcB, vn, flag);

    recurrence_kernel<<<dim3(256), blk, 0, stream>>>(qn, kn, vn, alphaT, betaT, st0,
                                                     outs, d_out, flag);

    gemm_bt128<<<dim3(2048 / 128, M / 128), blk, 0, stream>>>(outs, wob, d_out, M, 2048, 4096, 2, flag);
}

// Round 5
// 1983.560 us; speedup vs baseline: 2.5721x; 1.4815x over previous
//
#include <hip/hip_runtime.h>
#include <hip/hip_bf16.h>

typedef __attribute__((ext_vector_type(8))) __bf16 bf16x8;
typedef __attribute__((ext_vector_type(8))) short short8;
typedef __attribute__((ext_vector_type(4))) float floatx4;
using u16 = unsigned short;

#define GLOBAL_AS __attribute__((address_space(1)))
#define LDS_AS    __attribute__((address_space(3)))

__device__ __forceinline__ float b2f(u16 u) {
    union { unsigned int i; float f; } v; v.i = ((unsigned int)u) << 16; return v.f;
}
__device__ __forceinline__ u16 f2b(float f) {
    __hip_bfloat16 h = __float2bfloat16(f);
    return __builtin_bit_cast(u16, h);
}
__device__ __forceinline__ float ldf(const void* p, long i, bool isf32) {
    return isf32 ? ((const float*)p)[i] : b2f(((const u16*)p)[i]);
}
// async global->LDS, 16B per lane; lds base must be wave-uniform
__device__ __forceinline__ void gload_lds16(const void* g, void* l) {
    __builtin_amdgcn_global_load_lds((const GLOBAL_AS unsigned int*)g,
                                     (LDS_AS unsigned int*)l, 16, 0, 0);
}
// sum over 8 consecutive lanes, result in all 8 lanes (VALU DPP, no LDS)
__device__ __forceinline__ float red8(float x) {
    int xi, yi;
    xi = __builtin_bit_cast(int, x);
    yi = __builtin_amdgcn_update_dpp(xi, xi, 0xB1, 0xF, 0xF, false);   // quad_perm [1,0,3,2]
    x += __builtin_bit_cast(float, yi);
    xi = __builtin_bit_cast(int, x);
    yi = __builtin_amdgcn_update_dpp(xi, xi, 0x4E, 0xF, 0xF, false);   // quad_perm [2,3,0,1]
    x += __builtin_bit_cast(float, yi);
    xi = __builtin_bit_cast(int, x);
    yi = __builtin_amdgcn_update_dpp(xi, xi, 0x141, 0xF, 0xF, false);  // row_half_mirror
    x += __builtin_bit_cast(float, yi);
    return x;
}
__device__ __forceinline__ void unpack2(int d, float& lo, float& hi) {
    lo = __builtin_bit_cast(float, (int)((unsigned)d << 16));
    hi = __builtin_bit_cast(float, d & 0xffff0000);
}
__device__ __forceinline__ void unpack8(int4 d, float* f) {
    unpack2(d.x, f[0], f[1]); unpack2(d.y, f[2], f[3]);
    unpack2(d.z, f[4], f[5]); unpack2(d.w, f[6], f[7]);
}

// ---------------------------------------------------------------------------
// dtype detector (1 = inputs are f32)
// ---------------------------------------------------------------------------
__global__ void detect_dtype(const unsigned int* __restrict__ x, int* __restrict__ flag) {
    const int lane = threadIdx.x;
    int sane = 0;
    for (int i = lane; i < 256; i += 64) {
        const unsigned e = (x[i] >> 23) & 0xFF;
        sane += (e >= 100 && e <= 140) ? 1 : 0;
    }
#pragma unroll
    for (int m = 1; m < 64; m <<= 1) sane += __shfl_xor(sane, m, 64);
    if (lane == 0) *flag = (sane >= 128) ? 1 : 0;
}

// ---------------------------------------------------------------------------
// convert external tensor (f32 or bf16 per flag) -> bf16 buffer. n % 2048 == 0
// ---------------------------------------------------------------------------
__global__ __launch_bounds__(256) void cvt_bf16(
    const void* __restrict__ in, u16* __restrict__ out, long n, const int* __restrict__ flag) {
    const bool f32 = (*flag != 0);
    const long i = ((long)blockIdx.x * 256 + threadIdx.x) * 8;
    if (i >= n) return;
    if (f32) {
        const float* p = (const float*)in + i;
        floatx4 a = *(const floatx4*)p, b = *(const floatx4*)(p + 4);
        short8 o;
        o[0] = (short)f2b(a[0]); o[1] = (short)f2b(a[1]);
        o[2] = (short)f2b(a[2]); o[3] = (short)f2b(a[3]);
        o[4] = (short)f2b(b[0]); o[5] = (short)f2b(b[1]);
        o[6] = (short)f2b(b[2]); o[7] = (short)f2b(b[3]);
        *(short8*)(out + i) = o;
    } else {
        *(int4*)(out + i) = *(const int4*)((const u16*)in + i);
    }
}

// ---------------------------------------------------------------------------
// m97-class GEMM: C[M,N] = A[M,K] * B[N,K]^T, A/B bf16 row-major.
// 128x128 tile, BK=32, global_load_lds(16B), 4 waves x (4x4) 16x16x32 MFMA.
// cmode: 1 = f32 C, 3 = bf16 C, 2 = per-flag (f32 if flag else bf16)
// ---------------------------------------------------------------------------
__global__ __launch_bounds__(256) void gemm_bt128(
    const u16* __restrict__ A, const u16* __restrict__ B, void* __restrict__ C,
    int M, int N, int K, int cmode, const int* __restrict__ flag) {
    const bool c32 = (cmode == 1) || (cmode == 2 && *flag != 0);
    __shared__ __align__(16) u16 As[128 * 32];
    __shared__ __align__(16) u16 Bs[128 * 32];
    const int tid = threadIdx.x, lane = tid & 63, wave = tid >> 6;
    const int bm = blockIdx.y * 128, bn = blockIdx.x * 128;
    const int wm = (wave >> 1) * 64, wn = (wave & 1) * 64;
    const int fr = lane & 15, fq = lane >> 4;
    floatx4 acc[4][4] = {};

    const int srow = tid >> 2, scol = (tid & 3) * 8;       // 64 rows per call
    const long abase = (long)(bm + srow) * K + scol;
    const long bbase = (long)(bn + srow) * K + scol;
    char* lA = (char*)As + (tid & ~63) * 16;
    char* lB = (char*)Bs + (tid & ~63) * 16;

    for (int k0 = 0; k0 < K; k0 += 32) {
        __syncthreads();
        gload_lds16(A + abase + k0, lA);
        gload_lds16(A + abase + (long)64 * K + k0, lA + 4096);
        gload_lds16(B + bbase + k0, lB);
        gload_lds16(B + bbase + (long)64 * K + k0, lB + 4096);
        __syncthreads();
        bf16x8 af[4], bf[4];
#pragma unroll
        for (int i = 0; i < 4; i++) {
            af[i] = __builtin_bit_cast(bf16x8, *(const short8*)&As[(wm + i * 16 + fr) * 32 + fq * 8]);
            bf[i] = __builtin_bit_cast(bf16x8, *(const short8*)&Bs[(wn + i * 16 + fr) * 32 + fq * 8]);
        }
#pragma unroll
        for (int mi = 0; mi < 4; mi++)
#pragma unroll
            for (int ni = 0; ni < 4; ni++)
                acc[mi][ni] = __builtin_amdgcn_mfma_f32_16x16x32_bf16(
                    af[mi], bf[ni], acc[mi][ni], 0, 0, 0);
    }
#pragma unroll
    for (int mi = 0; mi < 4; mi++)
#pragma unroll
        for (int ni = 0; ni < 4; ni++)
#pragma unroll
            for (int r = 0; r < 4; r++) {
                const int m = bm + wm + mi * 16 + fq * 4 + r;
                const int n = bn + wn + ni * 16 + fr;
                const float val = acc[mi][ni][r];
                const long ci = (long)m * N + n;
                if (c32) ((float*)C)[ci] = val;
                else ((u16*)C)[ci] = f2b(val);
            }
}

// ---------------------------------------------------------------------------
// alpha/beta via MFMA: [4096,2048]x[32,2048]^T, sigmoid fused, transposed
// write to alphaT/betaT [b*16+h][T]. 64 blocks x (64m x 32n), BK=64.
// ---------------------------------------------------------------------------
__global__ __launch_bounds__(256) void ab_gemm(
    const u16* __restrict__ xb, const u16* __restrict__ wab,
    float* __restrict__ alphaT, float* __restrict__ betaT) {
    __shared__ __align__(16) u16 As[64 * 64];  // 8 KB
    __shared__ __align__(16) u16 Bs[32 * 64];  // 4 KB
    const int tid = threadIdx.x, lane = tid & 63, wave = tid >> 6;
    const int bm = blockIdx.x * 64;
    const int fr = lane & 15, fq = lane >> 4;
    floatx4 acc[2] = {};

    const int srow = tid >> 3, scol = (tid & 7) * 8;  // 32 rows x 64 cols per call
    char* lA = (char*)As + (tid & ~63) * 16;
    char* lB = (char*)Bs + (tid & ~63) * 16;

    for (int k0 = 0; k0 < 2048; k0 += 64) {
        __syncthreads();
        gload_lds16(xb + (long)(bm + srow) * 2048 + k0 + scol, lA);
        // rows 32..63 start at element 32*64=2048 -> byte offset 4096 (NOT 8192;
        // 8192 ran past As into Bs and corrupted the Wa/Wb tile — round-4 bug)
        gload_lds16(xb + (long)(bm + 32 + srow) * 2048 + k0 + scol, lA + 4096);
        gload_lds16(wab + (long)srow * 2048 + k0 + scol, lB);
        __syncthreads();
#pragma unroll
        for (int ks = 0; ks < 2; ks++) {
            bf16x8 af = __builtin_bit_cast(bf16x8,
                *(const short8*)&As[(wave * 16 + fr) * 64 + ks * 32 + fq * 8]);
#pragma unroll
            for (int nt = 0; nt < 2; nt++) {
                bf16x8 bf = __builtin_bit_cast(bf16x8,
                    *(const short8*)&Bs[(nt * 16 + fr) * 64 + ks * 32 + fq * 8]);
                acc[nt] = __builtin_amdgcn_mfma_f32_16x16x32_bf16(af, bf, acc[nt], 0, 0, 0);
            }
        }
    }
#pragma unroll
    for (int nt = 0; nt < 2; nt++)
#pragma unroll
        for (int r = 0; r < 4; r++) {
            const int m = bm + wave * 16 + fq * 4 + r;
            const int n = nt * 16 + fr;
            const int b = m >> 11, t = m & 2047;
            const float s = 1.f / (1.f + __expf(-acc[nt][r]));
            if (n < 16) alphaT[((long)b * 16 + n) * 2048 + t] = s;
            else betaT[((long)b * 16 + (n - 16)) * 2048 + t] = s;
        }
}

// ---------------------------------------------------------------------------
// causal depthwise conv K=4 + SiLU + per-head(128) L2 norm. pre is bf16.
// ---------------------------------------------------------------------------
__global__ __launch_bounds__(256) void conv_silu_norm(
    const u16* __restrict__ pre, const void* __restrict__ cw,
    const void* __restrict__ cb, u16* __restrict__ out, const int* __restrict__ flag) {
    const bool f32 = (*flag != 0);
    const int bt = blockIdx.x;
    const int t = bt & 2047;
    const int tid = threadIdx.x;
    const int c0 = tid * 8;
    float y[8];
    float ss = 0.f;
#pragma unroll
    for (int j = 0; j < 8; j++) {
        const int c = c0 + j;
        float acc = ldf(cb, c, f32);
#pragma unroll
        for (int i = 0; i < 4; i++) {
            if (t - 3 + i >= 0)
                acc += ldf(cw, c * 4 + i, f32) * b2f(pre[(long)(bt - 3 + i) * 2048 + c]);
        }
        const float s = acc / (1.f + __expf(-acc));
        y[j] = s;
        ss += s * s;
    }
#pragma unroll
    for (int m = 1; m < 16; m <<= 1) ss += __shfl_xor(ss, m, 64);
    const float inv = rsqrtf(ss + 1e-12f);
#pragma unroll
    for (int j = 0; j < 8; j++) out[(long)bt * 2048 + c0 + j] = f2b(y[j] * inv);
}

__global__ __launch_bounds__(256) void conv_silu_v(
    const u16* __restrict__ pre, const void* __restrict__ cw,
    const void* __restrict__ cb, u16* __restrict__ out, const int* __restrict__ flag) {
    const bool f32 = (*flag != 0);
    const int bt = blockIdx.x;
    const int t = bt & 2047;
    const int tid = threadIdx.x;
    const int c0 = tid * 16;
#pragma unroll
    for (int j = 0; j < 16; j++) {
        const int c = c0 + j;
        float acc = ldf(cb, c, f32);
#pragma unroll
        for (int i = 0; i < 4; i++) {
            if (t - 3 + i >= 0)
                acc += ldf(cw, c * 4 + i, f32) * b2f(pre[(long)(bt - 3 + i) * 4096 + c]);
        }
        out[(long)bt * 4096 + c] = f2b(acc / (1.f + __expf(-acc)));
    }
}

// ---------------------------------------------------------------------------
// Gated delta-rule recurrence, barrier-free steps (DPP k-reduction).
// 256 blocks = (b,h,vb); lane = vq*8+kg owns S[kg*16+j][v].
// ---------------------------------------------------------------------------
__global__ __launch_bounds__(256) void recurrence_kernel(
    const u16* __restrict__ qn, const u16* __restrict__ kn,
    const u16* __restrict__ vn, const float* __restrict__ alphaT,
    const float* __restrict__ betaT, const void* __restrict__ state_in,
    u16* __restrict__ outs, void* __restrict__ d_out, const int* __restrict__ flag) {
    const bool f32 = (*flag != 0);
    const int blk = blockIdx.x;
    const int vb = blk & 7, h = (blk >> 3) & 15, b = blk >> 7;
    const int tid = threadIdx.x, lane = tid & 63, wave = tid >> 6;
    const int kg = lane & 7, vq = lane >> 3;
    const int vloc = wave * 8 + vq;          // 0..31
    const int vglob = vb * 32 + vloc;

    float S[16];
    const long stbase = ((long)(b * 16 + h) * 128 + kg * 16) * 256 + vglob;
#pragma unroll
    for (int j = 0; j < 16; j++) S[j] = ldf(state_in, stbase + (long)j * 256, f32);

    __shared__ __align__(16) u16 kbuf[16 * 128];
    __shared__ __align__(16) u16 qbuf[16 * 128];
    __shared__ __align__(16) u16 vbuf[16 * 32];

    const long abase = (long)(b * 16 + h) * 2048;
    const int srow = tid >> 4, scol = (tid & 15) * 8;  // staging: 16 rows x 128
    char* lK = (char*)kbuf + (tid & ~63) * 16;
    char* lQ = (char*)qbuf + (tid & ~63) * 16;

    for (int c = 0; c < 128; ++c) {
        const int t0 = c * 16;
        __syncthreads();  // all waves done reading previous chunk
        const long gkq = ((long)b * 2048 + t0 + srow) * 2048 + h * 128 + scol;
        gload_lds16(kn + gkq, lK);
        gload_lds16(qn + gkq, lQ);
        if (tid < 64) {
            const long gv = ((long)b * 2048 + t0 + (lane >> 2)) * 4096 + h * 256 + vb * 32 + (lane & 3) * 8;
            gload_lds16(vn + gv, (char*)vbuf);
        }
        __syncthreads();  // staging complete (drains vmcnt)

#pragma unroll
        for (int tt = 0; tt < 16; ++tt) {
            const float a  = alphaT[abase + t0 + tt];
            const float bb = betaT[abase + t0 + tt];
            float kf[16], qf[16];
            unpack8(*(const int4*)(kbuf + tt * 128 + kg * 16), kf);
            unpack8(*(const int4*)(kbuf + tt * 128 + kg * 16 + 8), kf + 8);
            unpack8(*(const int4*)(qbuf + tt * 128 + kg * 16), qf);
            unpack8(*(const int4*)(qbuf + tt * 128 + kg * 16 + 8), qf + 8);
            float r0 = 0.f, r1 = 0.f;
#pragma unroll
            for (int j = 0; j < 8; j++) {
                r0 = fmaf(S[j], kf[j], r0);
                r1 = fmaf(S[8 + j], kf[8 + j], r1);
            }
            float r = red8(r0 + r1);
            const float vv = b2f(vbuf[tt * 32 + vloc]);
            const float err = fmaf(-a, r, vv);
            const float cc = bb * err;
            float o0 = 0.f, o1 = 0.f;
#pragma unroll
            for (int j = 0; j < 8; j++) {
                S[j] = fmaf(cc, kf[j], a * S[j]);
                S[8 + j] = fmaf(cc, kf[8 + j], a * S[8 + j]);
                o0 = fmaf(S[j], qf[j], o0);
                o1 = fmaf(S[8 + j], qf[8 + j], o1);
            }
            const float o = red8(o0 + o1);
            if (kg == 0)
                outs[((long)b * 2048 + t0 + tt) * 4096 + h * 256 + vglob] = f2b(o);
        }
    }
    // final state -> d_out at element offset B*T*H = 8388608
#pragma unroll
    for (int j = 0; j < 16; j++) {
        const long idx = 8388608L + stbase + (long)j * 256;
        if (f32) ((float*)d_out)[idx] = S[j];
        else ((u16*)d_out)[idx] = f2b(S[j]);
    }
}

// ---------------------------------------------------------------------------
extern "C" void kernel_launch(void* const* d_in, const int* in_sizes, int n_in,
                              void* d_out, int out_size, void* d_ws, size_t ws_size,
                              hipStream_t stream) {
    const void* x   = d_in[0];
    const void* st0 = d_in[1];
    const void* Wq  = d_in[2];
    const void* Wk  = d_in[3];
    const void* Wv  = d_in[4];
    const void* Wo  = d_in[5];
    const void* Wa  = d_in[6];
    const void* Wb  = d_in[7];
    const void* qcW = d_in[8];
    const void* qcB = d_in[9];
    const void* kcW = d_in[10];
    const void* kcB = d_in[11];
    const void* vcW = d_in[12];
    const void* vcB = d_in[13];

    const int M = 4096;  // B*T
    const long MB = 1024L * 1024L;
    char* w = (char*)d_ws;
    int*   flag   = (int*)w;                       // @0, 1KB pad
    float* alphaT = (float*)(w + 1024);            // 256 KB
    float* betaT  = (float*)(w + 1024 + 262144);   // 256 KB
    u16*   wab    = (u16*)(w + 1024 + 524288);     // 128 KB (Wa||Wb bf16)
    u16* xb    = (u16*)(w + 1 * MB);               // 16 MB  (reused for Wo later)
    u16* wqb   = (u16*)(w + 17 * MB);              // 8 MB
    u16* wkb   = (u16*)(w + 25 * MB);              // 8 MB
    u16* wvb   = (u16*)(w + 33 * MB);              // 16 MB
    u16* qpreb = (u16*)(w + 49 * MB);              // 16 MB
    u16* kpreb = (u16*)(w + 65 * MB);              // 16 MB
    u16* vpreb = (u16*)(w + 81 * MB);              // 32 MB
    u16* qn    = (u16*)(w + 113 * MB);             // 16 MB
    u16* kn    = (u16*)(w + 129 * MB);             // 16 MB
    u16* vn    = (u16*)(w + 145 * MB);             // 32 MB (ends 177 MB)
    u16* wob   = xb;                               // alias: x dead after proj GEMMs + ab_gemm
    u16* outs  = qpreb;                            // alias: 32 MB (qpreb+kpreb)

    dim3 blk(256);
    detect_dtype<<<dim3(1), dim3(64), 0, stream>>>((const unsigned int*)x, flag);

    cvt_bf16<<<dim3(4096), blk, 0, stream>>>(x,  xb,  8388608L, flag);
    cvt_bf16<<<dim3(2048), blk, 0, stream>>>(Wq, wqb, 4194304L, flag);
    cvt_bf16<<<dim3(2048), blk, 0, stream>>>(Wk, wkb, 4194304L, flag);
    cvt_bf16<<<dim3(4096), blk, 0, stream>>>(Wv, wvb, 8388608L, flag);
    cvt_bf16<<<dim3(16),   blk, 0, stream>>>(Wa, wab, 32768L, flag);
    cvt_bf16<<<dim3(16),   blk, 0, stream>>>(Wb, wab + 32768, 32768L, flag);

    gemm_bt128<<<dim3(2048 / 128, M / 128), blk, 0, stream>>>(xb, wqb, qpreb, M, 2048, 2048, 3, flag);
    gemm_bt128<<<dim3(2048 / 128, M / 128), blk, 0, stream>>>(xb, wkb, kpreb, M, 2048, 2048, 3, flag);
    gemm_bt128<<<dim3(4096 / 128, M / 128), blk, 0, stream>>>(xb, wvb, vpreb, M, 4096, 2048, 3, flag);
    ab_gemm<<<dim3(64), blk, 0, stream>>>(xb, wab, alphaT, betaT);

    cvt_bf16<<<dim3(4096), blk, 0, stream>>>(Wo, wob, 8388608L, flag);  // after all xb readers

    conv_silu_norm<<<dim3(M), blk, 0, stream>>>(qpreb, qcW, qcB, qn, flag);
    conv_silu_norm<<<dim3(M), blk, 0, stream>>>(kpreb, kcW, kcB, kn, flag);
    conv_silu_v<<<dim3(M), blk, 0, stream>>>(vpreb, vcW, vcB, vn, flag);

    recurrence_kernel<<<dim3(256), blk, 0, stream>>>(qn, kn, vn, alphaT, betaT, st0,
                                                     outs, d_out, flag);

    gemm_bt128<<<dim3(2048 / 128, M / 128), blk, 0, stream>>>(outs, wob, d_out, M, 2048, 4096, 2, flag);
}

// Round 6
// 1863.835 us; speedup vs baseline: 2.7373x; 1.0642x over previous
//
#include <hip/hip_runtime.h>
#include <hip/hip_bf16.h>

typedef __attribute__((ext_vector_type(8))) __bf16 bf16x8;
typedef __attribute__((ext_vector_type(8))) short short8;
typedef __attribute__((ext_vector_type(4))) float floatx4;
using u16 = unsigned short;

#define GLOBAL_AS __attribute__((address_space(1)))
#define LDS_AS    __attribute__((address_space(3)))

__device__ __forceinline__ float b2f(u16 u) {
    union { unsigned int i; float f; } v; v.i = ((unsigned int)u) << 16; return v.f;
}
__device__ __forceinline__ u16 f2b(float f) {
    __hip_bfloat16 h = __float2bfloat16(f);
    return __builtin_bit_cast(u16, h);
}
__device__ __forceinline__ float ldf(const void* p, long i, bool isf32) {
    return isf32 ? ((const float*)p)[i] : b2f(((const u16*)p)[i]);
}
// async global->LDS, 16B per lane; lds base must be wave-uniform
__device__ __forceinline__ void gload_lds16(const void* g, void* l) {
    __builtin_amdgcn_global_load_lds((const GLOBAL_AS unsigned int*)g,
                                     (LDS_AS unsigned int*)l, 16, 0, 0);
}
// sum over 8 consecutive lanes, result in all 8 lanes (VALU DPP, no LDS)
__device__ __forceinline__ float red8(float x) {
    int xi, yi;
    xi = __builtin_bit_cast(int, x);
    yi = __builtin_amdgcn_update_dpp(xi, xi, 0xB1, 0xF, 0xF, false);   // quad_perm [1,0,3,2]
    x += __builtin_bit_cast(float, yi);
    xi = __builtin_bit_cast(int, x);
    yi = __builtin_amdgcn_update_dpp(xi, xi, 0x4E, 0xF, 0xF, false);   // quad_perm [2,3,0,1]
    x += __builtin_bit_cast(float, yi);
    xi = __builtin_bit_cast(int, x);
    yi = __builtin_amdgcn_update_dpp(xi, xi, 0x141, 0xF, 0xF, false);  // row_half_mirror
    x += __builtin_bit_cast(float, yi);
    return x;
}
__device__ __forceinline__ void unpack2(int d, float& lo, float& hi) {
    lo = __builtin_bit_cast(float, (int)((unsigned)d << 16));
    hi = __builtin_bit_cast(float, d & 0xffff0000);
}
__device__ __forceinline__ void unpack8(int4 d, float* f) {
    unpack2(d.x, f[0], f[1]); unpack2(d.y, f[2], f[3]);
    unpack2(d.z, f[4], f[5]); unpack2(d.w, f[6], f[7]);
}

// ---------------------------------------------------------------------------
// dtype detector (1 = inputs are f32)
// ---------------------------------------------------------------------------
__global__ void detect_dtype(const unsigned int* __restrict__ x, int* __restrict__ flag) {
    const int lane = threadIdx.x;
    int sane = 0;
    for (int i = lane; i < 256; i += 64) {
        const unsigned e = (x[i] >> 23) & 0xFF;
        sane += (e >= 100 && e <= 140) ? 1 : 0;
    }
#pragma unroll
    for (int m = 1; m < 64; m <<= 1) sane += __shfl_xor(sane, m, 64);
    if (lane == 0) *flag = (sane >= 128) ? 1 : 0;
}

// ---------------------------------------------------------------------------
// convert external tensor (f32 or bf16 per flag) -> bf16 buffer. n % 2048 == 0
// ---------------------------------------------------------------------------
__global__ __launch_bounds__(256) void cvt_bf16(
    const void* __restrict__ in, u16* __restrict__ out, long n, const int* __restrict__ flag) {
    const bool f32 = (*flag != 0);
    const long i = ((long)blockIdx.x * 256 + threadIdx.x) * 8;
    if (i >= n) return;
    if (f32) {
        const float* p = (const float*)in + i;
        floatx4 a = *(const floatx4*)p, b = *(const floatx4*)(p + 4);
        short8 o;
        o[0] = (short)f2b(a[0]); o[1] = (short)f2b(a[1]);
        o[2] = (short)f2b(a[2]); o[3] = (short)f2b(a[3]);
        o[4] = (short)f2b(b[0]); o[5] = (short)f2b(b[1]);
        o[6] = (short)f2b(b[2]); o[7] = (short)f2b(b[3]);
        *(short8*)(out + i) = o;
    } else {
        *(int4*)(out + i) = *(const int4*)((const u16*)in + i);
    }
}

// ---------------------------------------------------------------------------
// m97-class GEMM: C[M,N] = A[M,K] * B[N,K]^T, A/B bf16 row-major.
// 128x128 tile, BK=32, global_load_lds(16B), 4 waves x (4x4) 16x16x32 MFMA.
// cmode: 1 = f32 C, 3 = bf16 C, 2 = per-flag (f32 if flag else bf16)
// ---------------------------------------------------------------------------
__global__ __launch_bounds__(256) void gemm_bt128(
    const u16* __restrict__ A, const u16* __restrict__ B, void* __restrict__ C,
    int M, int N, int K, int cmode, const int* __restrict__ flag) {
    const bool c32 = (cmode == 1) || (cmode == 2 && *flag != 0);
    __shared__ __align__(16) u16 As[128 * 32];
    __shared__ __align__(16) u16 Bs[128 * 32];
    const int tid = threadIdx.x, lane = tid & 63, wave = tid >> 6;
    const int bm = blockIdx.y * 128, bn = blockIdx.x * 128;
    const int wm = (wave >> 1) * 64, wn = (wave & 1) * 64;
    const int fr = lane & 15, fq = lane >> 4;
    floatx4 acc[4][4] = {};

    const int srow = tid >> 2, scol = (tid & 3) * 8;       // 64 rows per call
    const long abase = (long)(bm + srow) * K + scol;
    const long bbase = (long)(bn + srow) * K + scol;
    char* lA = (char*)As + (tid & ~63) * 16;
    char* lB = (char*)Bs + (tid & ~63) * 16;

    for (int k0 = 0; k0 < K; k0 += 32) {
        __syncthreads();
        gload_lds16(A + abase + k0, lA);
        gload_lds16(A + abase + (long)64 * K + k0, lA + 4096);
        gload_lds16(B + bbase + k0, lB);
        gload_lds16(B + bbase + (long)64 * K + k0, lB + 4096);
        __syncthreads();
        bf16x8 af[4], bf[4];
#pragma unroll
        for (int i = 0; i < 4; i++) {
            af[i] = __builtin_bit_cast(bf16x8, *(const short8*)&As[(wm + i * 16 + fr) * 32 + fq * 8]);
            bf[i] = __builtin_bit_cast(bf16x8, *(const short8*)&Bs[(wn + i * 16 + fr) * 32 + fq * 8]);
        }
#pragma unroll
        for (int mi = 0; mi < 4; mi++)
#pragma unroll
            for (int ni = 0; ni < 4; ni++)
                acc[mi][ni] = __builtin_amdgcn_mfma_f32_16x16x32_bf16(
                    af[mi], bf[ni], acc[mi][ni], 0, 0, 0);
    }
#pragma unroll
    for (int mi = 0; mi < 4; mi++)
#pragma unroll
        for (int ni = 0; ni < 4; ni++)
#pragma unroll
            for (int r = 0; r < 4; r++) {
                const int m = bm + wm + mi * 16 + fq * 4 + r;
                const int n = bn + wn + ni * 16 + fr;
                const float val = acc[mi][ni][r];
                const long ci = (long)m * N + n;
                if (c32) ((float*)C)[ci] = val;
                else ((u16*)C)[ci] = f2b(val);
            }
}

// ---------------------------------------------------------------------------
// alpha/beta via MFMA: [4096,2048]x[32,2048]^T, sigmoid fused, transposed
// write to alphaT/betaT [b*16+h][T]. 64 blocks x (64m x 32n), BK=64.
// ---------------------------------------------------------------------------
__global__ __launch_bounds__(256) void ab_gemm(
    const u16* __restrict__ xb, const u16* __restrict__ wab,
    float* __restrict__ alphaT, float* __restrict__ betaT) {
    __shared__ __align__(16) u16 As[64 * 64];  // 8 KB
    __shared__ __align__(16) u16 Bs[32 * 64];  // 4 KB
    const int tid = threadIdx.x, lane = tid & 63, wave = tid >> 6;
    const int bm = blockIdx.x * 64;
    const int fr = lane & 15, fq = lane >> 4;
    floatx4 acc[2] = {};

    const int srow = tid >> 3, scol = (tid & 7) * 8;  // 32 rows x 64 cols per call
    char* lA = (char*)As + (tid & ~63) * 16;
    char* lB = (char*)Bs + (tid & ~63) * 16;

    for (int k0 = 0; k0 < 2048; k0 += 64) {
        __syncthreads();
        gload_lds16(xb + (long)(bm + srow) * 2048 + k0 + scol, lA);
        // rows 32..63 start at element 32*64=2048 -> byte offset 4096
        gload_lds16(xb + (long)(bm + 32 + srow) * 2048 + k0 + scol, lA + 4096);
        gload_lds16(wab + (long)srow * 2048 + k0 + scol, lB);
        __syncthreads();
#pragma unroll
        for (int ks = 0; ks < 2; ks++) {
            bf16x8 af = __builtin_bit_cast(bf16x8,
                *(const short8*)&As[(wave * 16 + fr) * 64 + ks * 32 + fq * 8]);
#pragma unroll
            for (int nt = 0; nt < 2; nt++) {
                bf16x8 bf = __builtin_bit_cast(bf16x8,
                    *(const short8*)&Bs[(nt * 16 + fr) * 64 + ks * 32 + fq * 8]);
                acc[nt] = __builtin_amdgcn_mfma_f32_16x16x32_bf16(af, bf, acc[nt], 0, 0, 0);
            }
        }
    }
#pragma unroll
    for (int nt = 0; nt < 2; nt++)
#pragma unroll
        for (int r = 0; r < 4; r++) {
            const int m = bm + wave * 16 + fq * 4 + r;
            const int n = nt * 16 + fr;
            const int b = m >> 11, t = m & 2047;
            const float s = 1.f / (1.f + __expf(-acc[nt][r]));
            if (n < 16) alphaT[((long)b * 16 + n) * 2048 + t] = s;
            else betaT[((long)b * 16 + (n - 16)) * 2048 + t] = s;
        }
}

// ---------------------------------------------------------------------------
// causal depthwise conv K=4 + SiLU + per-head(128) L2 norm. pre is bf16.
// ---------------------------------------------------------------------------
__global__ __launch_bounds__(256) void conv_silu_norm(
    const u16* __restrict__ pre, const void* __restrict__ cw,
    const void* __restrict__ cb, u16* __restrict__ out, const int* __restrict__ flag) {
    const bool f32 = (*flag != 0);
    const int bt = blockIdx.x;
    const int t = bt & 2047;
    const int tid = threadIdx.x;
    const int c0 = tid * 8;
    float y[8];
    float ss = 0.f;
#pragma unroll
    for (int j = 0; j < 8; j++) {
        const int c = c0 + j;
        float acc = ldf(cb, c, f32);
#pragma unroll
        for (int i = 0; i < 4; i++) {
            if (t - 3 + i >= 0)
                acc += ldf(cw, c * 4 + i, f32) * b2f(pre[(long)(bt - 3 + i) * 2048 + c]);
        }
        const float s = acc / (1.f + __expf(-acc));
        y[j] = s;
        ss += s * s;
    }
#pragma unroll
    for (int m = 1; m < 16; m <<= 1) ss += __shfl_xor(ss, m, 64);
    const float inv = rsqrtf(ss + 1e-12f);
#pragma unroll
    for (int j = 0; j < 8; j++) out[(long)bt * 2048 + c0 + j] = f2b(y[j] * inv);
}

__global__ __launch_bounds__(256) void conv_silu_v(
    const u16* __restrict__ pre, const void* __restrict__ cw,
    const void* __restrict__ cb, u16* __restrict__ out, const int* __restrict__ flag) {
    const bool f32 = (*flag != 0);
    const int bt = blockIdx.x;
    const int t = bt & 2047;
    const int tid = threadIdx.x;
    const int c0 = tid * 16;
#pragma unroll
    for (int j = 0; j < 16; j++) {
        const int c = c0 + j;
        float acc = ldf(cb, c, f32);
#pragma unroll
        for (int i = 0; i < 4; i++) {
            if (t - 3 + i >= 0)
                acc += ldf(cw, c * 4 + i, f32) * b2f(pre[(long)(bt - 3 + i) * 4096 + c]);
        }
        out[(long)bt * 4096 + c] = f2b(acc / (1.f + __expf(-acc)));
    }
}

// ---------------------------------------------------------------------------
// Gated delta-rule recurrence, barrier-free steps (DPP k-reduction).
// 256 blocks = (b,h,vb); lane = vq*8+kg owns S[kg*16+j][v].
// R6 change: alpha/beta hoisted to ONE coalesced load per 16-step chunk per
// wave (lane i<16 holds a[t0+i]); per-step scalar extracted via v_readlane
// with literal index -> zero VMEM on the per-step critical path.
// ---------------------------------------------------------------------------
__global__ __launch_bounds__(256) void recurrence_kernel(
    const u16* __restrict__ qn, const u16* __restrict__ kn,
    const u16* __restrict__ vn, const float* __restrict__ alphaT,
    const float* __restrict__ betaT, const void* __restrict__ state_in,
    u16* __restrict__ outs, void* __restrict__ d_out, const int* __restrict__ flag) {
    const bool f32 = (*flag != 0);
    const int blk = blockIdx.x;
    const int vb = blk & 7, h = (blk >> 3) & 15, b = blk >> 7;
    const int tid = threadIdx.x, lane = tid & 63, wave = tid >> 6;
    const int kg = lane & 7, vq = lane >> 3;
    const int vloc = wave * 8 + vq;          // 0..31
    const int vglob = vb * 32 + vloc;

    float S[16];
    const long stbase = ((long)(b * 16 + h) * 128 + kg * 16) * 256 + vglob;
#pragma unroll
    for (int j = 0; j < 16; j++) S[j] = ldf(state_in, stbase + (long)j * 256, f32);

    __shared__ __align__(16) u16 kbuf[16 * 128];
    __shared__ __align__(16) u16 qbuf[16 * 128];
    __shared__ __align__(16) u16 vbuf[16 * 32];

    const long abase = (long)(b * 16 + h) * 2048;
    const int srow = tid >> 4, scol = (tid & 15) * 8;  // staging: 16 rows x 128
    char* lK = (char*)kbuf + (tid & ~63) * 16;
    char* lQ = (char*)qbuf + (tid & ~63) * 16;

    for (int c = 0; c < 128; ++c) {
        const int t0 = c * 16;
        // chunk-hoisted alpha/beta: lane i<16 holds value for step t0+i
        const float aw = alphaT[abase + t0 + (lane & 15)];
        const float bw = betaT[abase + t0 + (lane & 15)];
        __syncthreads();  // all waves done reading previous chunk
        const long gkq = ((long)b * 2048 + t0 + srow) * 2048 + h * 128 + scol;
        gload_lds16(kn + gkq, lK);
        gload_lds16(qn + gkq, lQ);
        if (tid < 64) {
            const long gv = ((long)b * 2048 + t0 + (lane >> 2)) * 4096 + h * 256 + vb * 32 + (lane & 3) * 8;
            gload_lds16(vn + gv, (char*)vbuf);
        }
        __syncthreads();  // staging complete (drains vmcnt)

#pragma unroll
        for (int tt = 0; tt < 16; ++tt) {
            const float a = __builtin_bit_cast(float,
                __builtin_amdgcn_readlane(__builtin_bit_cast(int, aw), tt));
            const float bb = __builtin_bit_cast(float,
                __builtin_amdgcn_readlane(__builtin_bit_cast(int, bw), tt));
            float kf[16], qf[16];
            unpack8(*(const int4*)(kbuf + tt * 128 + kg * 16), kf);
            unpack8(*(const int4*)(kbuf + tt * 128 + kg * 16 + 8), kf + 8);
            unpack8(*(const int4*)(qbuf + tt * 128 + kg * 16), qf);
            unpack8(*(const int4*)(qbuf + tt * 128 + kg * 16 + 8), qf + 8);
            float r0 = 0.f, r1 = 0.f;
#pragma unroll
            for (int j = 0; j < 8; j++) {
                r0 = fmaf(S[j], kf[j], r0);
                r1 = fmaf(S[8 + j], kf[8 + j], r1);
            }
            float r = red8(r0 + r1);
            const float vv = b2f(vbuf[tt * 32 + vloc]);
            const float err = fmaf(-a, r, vv);
            const float cc = bb * err;
            float o0 = 0.f, o1 = 0.f;
#pragma unroll
            for (int j = 0; j < 8; j++) {
                S[j] = fmaf(cc, kf[j], a * S[j]);
                S[8 + j] = fmaf(cc, kf[8 + j], a * S[8 + j]);
                o0 = fmaf(S[j], qf[j], o0);
                o1 = fmaf(S[8 + j], qf[8 + j], o1);
            }
            const float o = red8(o0 + o1);
            if (kg == 0)
                outs[((long)b * 2048 + t0 + tt) * 4096 + h * 256 + vglob] = f2b(o);
        }
    }
    // final state -> d_out at element offset B*T*H = 8388608
#pragma unroll
    for (int j = 0; j < 16; j++) {
        const long idx = 8388608L + stbase + (long)j * 256;
        if (f32) ((float*)d_out)[idx] = S[j];
        else ((u16*)d_out)[idx] = f2b(S[j]);
    }
}

// ---------------------------------------------------------------------------
extern "C" void kernel_launch(void* const* d_in, const int* in_sizes, int n_in,
                              void* d_out, int out_size, void* d_ws, size_t ws_size,
                              hipStream_t stream) {
    const void* x   = d_in[0];
    const void* st0 = d_in[1];
    const void* Wq  = d_in[2];
    const void* Wk  = d_in[3];
    const void* Wv  = d_in[4];
    const void* Wo  = d_in[5];
    const void* Wa  = d_in[6];
    const void* Wb  = d_in[7];
    const void* qcW = d_in[8];
    const void* qcB = d_in[9];
    const void* kcW = d_in[10];
    const void* kcB = d_in[11];
    const void* vcW = d_in[12];
    const void* vcB = d_in[13];

    const int M = 4096;  // B*T
    const long MB = 1024L * 1024L;
    char* w = (char*)d_ws;
    int*   flag   = (int*)w;                       // @0, 1KB pad
    float* alphaT = (float*)(w + 1024);            // 256 KB
    float* betaT  = (float*)(w + 1024 + 262144);   // 256 KB
    u16*   wab    = (u16*)(w + 1024 + 524288);     // 128 KB (Wa||Wb bf16)
    u16* xb    = (u16*)(w + 1 * MB);               // 16 MB  (reused for Wo later)
    u16* wqb   = (u16*)(w + 17 * MB);              // 8 MB
    u16* wkb   = (u16*)(w + 25 * MB);              // 8 MB
    u16* wvb   = (u16*)(w + 33 * MB);              // 16 MB
    u16* qpreb = (u16*)(w + 49 * MB);              // 16 MB
    u16* kpreb = (u16*)(w + 65 * MB);              // 16 MB
    u16* vpreb = (u16*)(w + 81 * MB);              // 32 MB
    u16* qn    = (u16*)(w + 113 * MB);             // 16 MB
    u16* kn    = (u16*)(w + 129 * MB);             // 16 MB
    u16* vn    = (u16*)(w + 145 * MB);             // 32 MB (ends 177 MB)
    u16* wob   = xb;                               // alias: x dead after proj GEMMs + ab_gemm
    u16* outs  = qpreb;                            // alias: 32 MB (qpreb+kpreb)

    dim3 blk(256);
    detect_dtype<<<dim3(1), dim3(64), 0, stream>>>((const unsigned int*)x, flag);

    cvt_bf16<<<dim3(4096), blk, 0, stream>>>(x,  xb,  8388608L, flag);
    cvt_bf16<<<dim3(2048), blk, 0, stream>>>(Wq, wqb, 4194304L, flag);
    cvt_bf16<<<dim3(2048), blk, 0, stream>>>(Wk, wkb, 4194304L, flag);
    cvt_bf16<<<dim3(4096), blk, 0, stream>>>(Wv, wvb, 8388608L, flag);
    cvt_bf16<<<dim3(16),   blk, 0, stream>>>(Wa, wab, 32768L, flag);
    cvt_bf16<<<dim3(16),   blk, 0, stream>>>(Wb, wab + 32768, 32768L, flag);

    gemm_bt128<<<dim3(2048 / 128, M / 128), blk, 0, stream>>>(xb, wqb, qpreb, M, 2048, 2048, 3, flag);
    gemm_bt128<<<dim3(2048 / 128, M / 128), blk, 0, stream>>>(xb, wkb, kpreb, M, 2048, 2048, 3, flag);
    gemm_bt128<<<dim3(4096 / 128, M / 128), blk, 0, stream>>>(xb, wvb, vpreb, M, 4096, 2048, 3, flag);
    ab_gemm<<<dim3(64), blk, 0, stream>>>(xb, wab, alphaT, betaT);

    cvt_bf16<<<dim3(4096), blk, 0, stream>>>(Wo, wob, 8388608L, flag);  // after all xb readers

    conv_silu_norm<<<dim3(M), blk, 0, stream>>>(qpreb, qcW, qcB, qn, flag);
    conv_silu_norm<<<dim3(M), blk, 0, stream>>>(kpreb, kcW, kcB, kn, flag);
    conv_silu_v<<<dim3(M), blk, 0, stream>>>(vpreb, vcW, vcB, vn, flag);

    recurrence_kernel<<<dim3(256), blk, 0, stream>>>(qn, kn, vn, alphaT, betaT, st0,
                                                     outs, d_out, flag);

    gemm_bt128<<<dim3(2048 / 128, M / 128), blk, 0, stream>>>(outs, wob, d_out, M, 2048, 4096, 2, flag);
}

// Round 7
// 1826.353 us; speedup vs baseline: 2.7935x; 1.0205x over previous
//
#include <hip/hip_runtime.h>
#include <hip/hip_bf16.h>

typedef __attribute__((ext_vector_type(8))) __bf16 bf16x8;
typedef __attribute__((ext_vector_type(8))) short short8;
typedef __attribute__((ext_vector_type(4))) float floatx4;
using u16 = unsigned short;

#define GLOBAL_AS __attribute__((address_space(1)))
#define LDS_AS    __attribute__((address_space(3)))

__device__ __forceinline__ float b2f(u16 u) {
    union { unsigned int i; float f; } v; v.i = ((unsigned int)u) << 16; return v.f;
}
__device__ __forceinline__ u16 f2b(float f) {
    __hip_bfloat16 h = __float2bfloat16(f);
    return __builtin_bit_cast(u16, h);
}
__device__ __forceinline__ float ldf(const void* p, long i, bool isf32) {
    return isf32 ? ((const float*)p)[i] : b2f(((const u16*)p)[i]);
}
// async global->LDS, 16B per lane; lds base must be wave-uniform
__device__ __forceinline__ void gload_lds16(const void* g, void* l) {
    __builtin_amdgcn_global_load_lds((const GLOBAL_AS unsigned int*)g,
                                     (LDS_AS unsigned int*)l, 16, 0, 0);
}
// sum over 8 consecutive lanes, result in all 8 lanes (VALU DPP, no LDS)
__device__ __forceinline__ float red8(float x) {
    int xi, yi;
    xi = __builtin_bit_cast(int, x);
    yi = __builtin_amdgcn_update_dpp(xi, xi, 0xB1, 0xF, 0xF, false);   // quad_perm [1,0,3,2]
    x += __builtin_bit_cast(float, yi);
    xi = __builtin_bit_cast(int, x);
    yi = __builtin_amdgcn_update_dpp(xi, xi, 0x4E, 0xF, 0xF, false);   // quad_perm [2,3,0,1]
    x += __builtin_bit_cast(float, yi);
    xi = __builtin_bit_cast(int, x);
    yi = __builtin_amdgcn_update_dpp(xi, xi, 0x141, 0xF, 0xF, false);  // row_half_mirror
    x += __builtin_bit_cast(float, yi);
    return x;
}
__device__ __forceinline__ void unpack2(int d, float& lo, float& hi) {
    lo = __builtin_bit_cast(float, (int)((unsigned)d << 16));
    hi = __builtin_bit_cast(float, d & 0xffff0000);
}
__device__ __forceinline__ void unpack8(int4 d, float* f) {
    unpack2(d.x, f[0], f[1]); unpack2(d.y, f[2], f[3]);
    unpack2(d.z, f[4], f[5]); unpack2(d.w, f[6], f[7]);
}

// ---------------------------------------------------------------------------
// dtype detector (1 = inputs are f32)
// ---------------------------------------------------------------------------
__global__ void detect_dtype(const unsigned int* __restrict__ x, int* __restrict__ flag) {
    const int lane = threadIdx.x;
    int sane = 0;
    for (int i = lane; i < 256; i += 64) {
        const unsigned e = (x[i] >> 23) & 0xFF;
        sane += (e >= 100 && e <= 140) ? 1 : 0;
    }
#pragma unroll
    for (int m = 1; m < 64; m <<= 1) sane += __shfl_xor(sane, m, 64);
    if (lane == 0) *flag = (sane >= 128) ? 1 : 0;
}

// ---------------------------------------------------------------------------
// convert external tensor (f32 or bf16 per flag) -> bf16 buffer. n % 2048 == 0
// ---------------------------------------------------------------------------
__global__ __launch_bounds__(256) void cvt_bf16(
    const void* __restrict__ in, u16* __restrict__ out, long n, const int* __restrict__ flag) {
    const bool f32 = (*flag != 0);
    const long i = ((long)blockIdx.x * 256 + threadIdx.x) * 8;
    if (i >= n) return;
    if (f32) {
        const float* p = (const float*)in + i;
        floatx4 a = *(const floatx4*)p, b = *(const floatx4*)(p + 4);
        short8 o;
        o[0] = (short)f2b(a[0]); o[1] = (short)f2b(a[1]);
        o[2] = (short)f2b(a[2]); o[3] = (short)f2b(a[3]);
        o[4] = (short)f2b(b[0]); o[5] = (short)f2b(b[1]);
        o[6] = (short)f2b(b[2]); o[7] = (short)f2b(b[3]);
        *(short8*)(out + i) = o;
    } else {
        *(int4*)(out + i) = *(const int4*)((const u16*)in + i);
    }
}

// ---------------------------------------------------------------------------
// m97-class GEMM: C[M,N] = A[M,K] * B[N,K]^T, A/B bf16 row-major.
// 128x128 tile, BK=32, global_load_lds(16B), 4 waves x (4x4) 16x16x32 MFMA.
// cmode: 1 = f32 C, 3 = bf16 C, 2 = per-flag (f32 if flag else bf16)
// ---------------------------------------------------------------------------
__global__ __launch_bounds__(256) void gemm_bt128(
    const u16* __restrict__ A, const u16* __restrict__ B, void* __restrict__ C,
    int M, int N, int K, int cmode, const int* __restrict__ flag) {
    const bool c32 = (cmode == 1) || (cmode == 2 && *flag != 0);
    __shared__ __align__(16) u16 As[128 * 32];
    __shared__ __align__(16) u16 Bs[128 * 32];
    const int tid = threadIdx.x, lane = tid & 63, wave = tid >> 6;
    const int bm = blockIdx.y * 128, bn = blockIdx.x * 128;
    const int wm = (wave >> 1) * 64, wn = (wave & 1) * 64;
    const int fr = lane & 15, fq = lane >> 4;
    floatx4 acc[4][4] = {};

    const int srow = tid >> 2, scol = (tid & 3) * 8;       // 64 rows per call
    const long abase = (long)(bm + srow) * K + scol;
    const long bbase = (long)(bn + srow) * K + scol;
    char* lA = (char*)As + (tid & ~63) * 16;
    char* lB = (char*)Bs + (tid & ~63) * 16;

    for (int k0 = 0; k0 < K; k0 += 32) {
        __syncthreads();
        gload_lds16(A + abase + k0, lA);
        gload_lds16(A + abase + (long)64 * K + k0, lA + 4096);
        gload_lds16(B + bbase + k0, lB);
        gload_lds16(B + bbase + (long)64 * K + k0, lB + 4096);
        __syncthreads();
        bf16x8 af[4], bf[4];
#pragma unroll
        for (int i = 0; i < 4; i++) {
            af[i] = __builtin_bit_cast(bf16x8, *(const short8*)&As[(wm + i * 16 + fr) * 32 + fq * 8]);
            bf[i] = __builtin_bit_cast(bf16x8, *(const short8*)&Bs[(wn + i * 16 + fr) * 32 + fq * 8]);
        }
#pragma unroll
        for (int mi = 0; mi < 4; mi++)
#pragma unroll
            for (int ni = 0; ni < 4; ni++)
                acc[mi][ni] = __builtin_amdgcn_mfma_f32_16x16x32_bf16(
                    af[mi], bf[ni], acc[mi][ni], 0, 0, 0);
    }
#pragma unroll
    for (int mi = 0; mi < 4; mi++)
#pragma unroll
        for (int ni = 0; ni < 4; ni++)
#pragma unroll
            for (int r = 0; r < 4; r++) {
                const int m = bm + wm + mi * 16 + fq * 4 + r;
                const int n = bn + wn + ni * 16 + fr;
                const float val = acc[mi][ni][r];
                const long ci = (long)m * N + n;
                if (c32) ((float*)C)[ci] = val;
                else ((u16*)C)[ci] = f2b(val);
            }
}

// ---------------------------------------------------------------------------
// alpha/beta via MFMA: [4096,2048]x[32,2048]^T, sigmoid fused, transposed
// write to alphaT/betaT [b*16+h][T]. 64 blocks x (64m x 32n), BK=64.
// ---------------------------------------------------------------------------
__global__ __launch_bounds__(256) void ab_gemm(
    const u16* __restrict__ xb, const u16* __restrict__ wab,
    float* __restrict__ alphaT, float* __restrict__ betaT) {
    __shared__ __align__(16) u16 As[64 * 64];  // 8 KB
    __shared__ __align__(16) u16 Bs[32 * 64];  // 4 KB
    const int tid = threadIdx.x, lane = tid & 63, wave = tid >> 6;
    const int bm = blockIdx.x * 64;
    const int fr = lane & 15, fq = lane >> 4;
    floatx4 acc[2] = {};

    const int srow = tid >> 3, scol = (tid & 7) * 8;  // 32 rows x 64 cols per call
    char* lA = (char*)As + (tid & ~63) * 16;
    char* lB = (char*)Bs + (tid & ~63) * 16;

    for (int k0 = 0; k0 < 2048; k0 += 64) {
        __syncthreads();
        gload_lds16(xb + (long)(bm + srow) * 2048 + k0 + scol, lA);
        // rows 32..63 start at element 32*64=2048 -> byte offset 4096
        gload_lds16(xb + (long)(bm + 32 + srow) * 2048 + k0 + scol, lA + 4096);
        gload_lds16(wab + (long)srow * 2048 + k0 + scol, lB);
        __syncthreads();
#pragma unroll
        for (int ks = 0; ks < 2; ks++) {
            bf16x8 af = __builtin_bit_cast(bf16x8,
                *(const short8*)&As[(wave * 16 + fr) * 64 + ks * 32 + fq * 8]);
#pragma unroll
            for (int nt = 0; nt < 2; nt++) {
                bf16x8 bf = __builtin_bit_cast(bf16x8,
                    *(const short8*)&Bs[(nt * 16 + fr) * 64 + ks * 32 + fq * 8]);
                acc[nt] = __builtin_amdgcn_mfma_f32_16x16x32_bf16(af, bf, acc[nt], 0, 0, 0);
            }
        }
    }
#pragma unroll
    for (int nt = 0; nt < 2; nt++)
#pragma unroll
        for (int r = 0; r < 4; r++) {
            const int m = bm + wave * 16 + fq * 4 + r;
            const int n = nt * 16 + fr;
            const int b = m >> 11, t = m & 2047;
            const float s = 1.f / (1.f + __expf(-acc[nt][r]));
            if (n < 16) alphaT[((long)b * 16 + n) * 2048 + t] = s;
            else betaT[((long)b * 16 + (n - 16)) * 2048 + t] = s;
        }
}

// ---------------------------------------------------------------------------
// causal depthwise conv K=4 + SiLU + per-head(128) L2 norm. pre is bf16.
// ---------------------------------------------------------------------------
__global__ __launch_bounds__(256) void conv_silu_norm(
    const u16* __restrict__ pre, const void* __restrict__ cw,
    const void* __restrict__ cb, u16* __restrict__ out, const int* __restrict__ flag) {
    const bool f32 = (*flag != 0);
    const int bt = blockIdx.x;
    const int t = bt & 2047;
    const int tid = threadIdx.x;
    const int c0 = tid * 8;
    float y[8];
    float ss = 0.f;
#pragma unroll
    for (int j = 0; j < 8; j++) {
        const int c = c0 + j;
        float acc = ldf(cb, c, f32);
#pragma unroll
        for (int i = 0; i < 4; i++) {
            if (t - 3 + i >= 0)
                acc += ldf(cw, c * 4 + i, f32) * b2f(pre[(long)(bt - 3 + i) * 2048 + c]);
        }
        const float s = acc / (1.f + __expf(-acc));
        y[j] = s;
        ss += s * s;
    }
#pragma unroll
    for (int m = 1; m < 16; m <<= 1) ss += __shfl_xor(ss, m, 64);
    const float inv = rsqrtf(ss + 1e-12f);
#pragma unroll
    for (int j = 0; j < 8; j++) out[(long)bt * 2048 + c0 + j] = f2b(y[j] * inv);
}

__global__ __launch_bounds__(256) void conv_silu_v(
    const u16* __restrict__ pre, const void* __restrict__ cw,
    const void* __restrict__ cb, u16* __restrict__ out, const int* __restrict__ flag) {
    const bool f32 = (*flag != 0);
    const int bt = blockIdx.x;
    const int t = bt & 2047;
    const int tid = threadIdx.x;
    const int c0 = tid * 16;
#pragma unroll
    for (int j = 0; j < 16; j++) {
        const int c = c0 + j;
        float acc = ldf(cb, c, f32);
#pragma unroll
        for (int i = 0; i < 4; i++) {
            if (t - 3 + i >= 0)
                acc += ldf(cw, c * 4 + i, f32) * b2f(pre[(long)(bt - 3 + i) * 4096 + c]);
        }
        out[(long)bt * 4096 + c] = f2b(acc / (1.f + __expf(-acc)));
    }
}

// ---------------------------------------------------------------------------
// Gated delta-rule recurrence, barrier-free steps (DPP k-reduction).
// 256 blocks = (b,h,vb); lane = vq*8+kg owns S[kg*16+j][v].
// R7 change: explicit 1-step software pipeline — step tt+1's k/q int4s and
// v value are loaded into registers BEFORE step tt's compute, so ~5 LDS
// reads stay in flight under the ~220cyc of VALU work (VGPR 48->~70, no
// occupancy impact at 1 block/CU).
// ---------------------------------------------------------------------------
__global__ __launch_bounds__(256) void recurrence_kernel(
    const u16* __restrict__ qn, const u16* __restrict__ kn,
    const u16* __restrict__ vn, const float* __restrict__ alphaT,
    const float* __restrict__ betaT, const void* __restrict__ state_in,
    u16* __restrict__ outs, void* __restrict__ d_out, const int* __restrict__ flag) {
    const bool f32 = (*flag != 0);
    const int blk = blockIdx.x;
    const int vb = blk & 7, h = (blk >> 3) & 15, b = blk >> 7;
    const int tid = threadIdx.x, lane = tid & 63, wave = tid >> 6;
    const int kg = lane & 7, vq = lane >> 3;
    const int vloc = wave * 8 + vq;          // 0..31
    const int vglob = vb * 32 + vloc;

    float S[16];
    const long stbase = ((long)(b * 16 + h) * 128 + kg * 16) * 256 + vglob;
#pragma unroll
    for (int j = 0; j < 16; j++) S[j] = ldf(state_in, stbase + (long)j * 256, f32);

    __shared__ __align__(16) u16 kbuf[16 * 128];
    __shared__ __align__(16) u16 qbuf[16 * 128];
    __shared__ __align__(16) u16 vbuf[16 * 32];

    const long abase = (long)(b * 16 + h) * 2048;
    const int srow = tid >> 4, scol = (tid & 15) * 8;  // staging: 16 rows x 128
    char* lK = (char*)kbuf + (tid & ~63) * 16;
    char* lQ = (char*)qbuf + (tid & ~63) * 16;

    for (int c = 0; c < 128; ++c) {
        const int t0 = c * 16;
        // chunk-hoisted alpha/beta: lane i<16 holds value for step t0+i
        const float aw = alphaT[abase + t0 + (lane & 15)];
        const float bw = betaT[abase + t0 + (lane & 15)];
        __syncthreads();  // all waves done reading previous chunk
        const long gkq = ((long)b * 2048 + t0 + srow) * 2048 + h * 128 + scol;
        gload_lds16(kn + gkq, lK);
        gload_lds16(qn + gkq, lQ);
        if (tid < 64) {
            const long gv = ((long)b * 2048 + t0 + (lane >> 2)) * 4096 + h * 256 + vb * 32 + (lane & 3) * 8;
            gload_lds16(vn + gv, (char*)vbuf);
        }
        __syncthreads();  // staging complete (drains vmcnt)

        // software pipeline: preload step 0
        int4 kA = *(const int4*)(kbuf + kg * 16);
        int4 kB = *(const int4*)(kbuf + kg * 16 + 8);
        int4 qA = *(const int4*)(qbuf + kg * 16);
        int4 qB = *(const int4*)(qbuf + kg * 16 + 8);
        u16 vcur = vbuf[vloc];

#pragma unroll
        for (int tt = 0; tt < 16; ++tt) {
            // issue next step's LDS reads BEFORE this step's compute
            int4 kA_n, kB_n, qA_n, qB_n;
            u16 v_n;
            if (tt < 15) {
                kA_n = *(const int4*)(kbuf + (tt + 1) * 128 + kg * 16);
                kB_n = *(const int4*)(kbuf + (tt + 1) * 128 + kg * 16 + 8);
                qA_n = *(const int4*)(qbuf + (tt + 1) * 128 + kg * 16);
                qB_n = *(const int4*)(qbuf + (tt + 1) * 128 + kg * 16 + 8);
                v_n  = vbuf[(tt + 1) * 32 + vloc];
            }
            const float a = __builtin_bit_cast(float,
                __builtin_amdgcn_readlane(__builtin_bit_cast(int, aw), tt));
            const float bb = __builtin_bit_cast(float,
                __builtin_amdgcn_readlane(__builtin_bit_cast(int, bw), tt));
            float kf[16], qf[16];
            unpack8(kA, kf);
            unpack8(kB, kf + 8);
            unpack8(qA, qf);
            unpack8(qB, qf + 8);
            float r0 = 0.f, r1 = 0.f;
#pragma unroll
            for (int j = 0; j < 8; j++) {
                r0 = fmaf(S[j], kf[j], r0);
                r1 = fmaf(S[8 + j], kf[8 + j], r1);
            }
            float r = red8(r0 + r1);
            const float vv = b2f(vcur);
            const float err = fmaf(-a, r, vv);
            const float cc = bb * err;
            float o0 = 0.f, o1 = 0.f;
#pragma unroll
            for (int j = 0; j < 8; j++) {
                S[j] = fmaf(cc, kf[j], a * S[j]);
                S[8 + j] = fmaf(cc, kf[8 + j], a * S[8 + j]);
                o0 = fmaf(S[j], qf[j], o0);
                o1 = fmaf(S[8 + j], qf[8 + j], o1);
            }
            const float o = red8(o0 + o1);
            if (kg == 0)
                outs[((long)b * 2048 + t0 + tt) * 4096 + h * 256 + vglob] = f2b(o);
            if (tt < 15) { kA = kA_n; kB = kB_n; qA = qA_n; qB = qB_n; vcur = v_n; }
        }
    }
    // final state -> d_out at element offset B*T*H = 8388608
#pragma unroll
    for (int j = 0; j < 16; j++) {
        const long idx = 8388608L + stbase + (long)j * 256;
        if (f32) ((float*)d_out)[idx] = S[j];
        else ((u16*)d_out)[idx] = f2b(S[j]);
    }
}

// ---------------------------------------------------------------------------
extern "C" void kernel_launch(void* const* d_in, const int* in_sizes, int n_in,
                              void* d_out, int out_size, void* d_ws, size_t ws_size,
                              hipStream_t stream) {
    const void* x   = d_in[0];
    const void* st0 = d_in[1];
    const void* Wq  = d_in[2];
    const void* Wk  = d_in[3];
    const void* Wv  = d_in[4];
    const void* Wo  = d_in[5];
    const void* Wa  = d_in[6];
    const void* Wb  = d_in[7];
    const void* qcW = d_in[8];
    const void* qcB = d_in[9];
    const void* kcW = d_in[10];
    const void* kcB = d_in[11];
    const void* vcW = d_in[12];
    const void* vcB = d_in[13];

    const int M = 4096;  // B*T
    const long MB = 1024L * 1024L;
    char* w = (char*)d_ws;
    int*   flag   = (int*)w;                       // @0, 1KB pad
    float* alphaT = (float*)(w + 1024);            // 256 KB
    float* betaT  = (float*)(w + 1024 + 262144);   // 256 KB
    u16*   wab    = (u16*)(w + 1024 + 524288);     // 128 KB (Wa||Wb bf16)
    u16* xb    = (u16*)(w + 1 * MB);               // 16 MB  (reused for Wo later)
    u16* wqb   = (u16*)(w + 17 * MB);              // 8 MB
    u16* wkb   = (u16*)(w + 25 * MB);              // 8 MB
    u16* wvb   = (u16*)(w + 33 * MB);              // 16 MB
    u16* qpreb = (u16*)(w + 49 * MB);              // 16 MB
    u16* kpreb = (u16*)(w + 65 * MB);              // 16 MB
    u16* vpreb = (u16*)(w + 81 * MB);              // 32 MB
    u16* qn    = (u16*)(w + 113 * MB);             // 16 MB
    u16* kn    = (u16*)(w + 129 * MB);             // 16 MB
    u16* vn    = (u16*)(w + 145 * MB);             // 32 MB (ends 177 MB)
    u16* wob   = xb;                               // alias: x dead after proj GEMMs + ab_gemm
    u16* outs  = qpreb;                            // alias: 32 MB (qpreb+kpreb)

    dim3 blk(256);
    detect_dtype<<<dim3(1), dim3(64), 0, stream>>>((const unsigned int*)x, flag);

    cvt_bf16<<<dim3(4096), blk, 0, stream>>>(x,  xb,  8388608L, flag);
    cvt_bf16<<<dim3(2048), blk, 0, stream>>>(Wq, wqb, 4194304L, flag);
    cvt_bf16<<<dim3(2048), blk, 0, stream>>>(Wk, wkb, 4194304L, flag);
    cvt_bf16<<<dim3(4096), blk, 0, stream>>>(Wv, wvb, 8388608L, flag);
    cvt_bf16<<<dim3(16),   blk, 0, stream>>>(Wa, wab, 32768L, flag);
    cvt_bf16<<<dim3(16),   blk, 0, stream>>>(Wb, wab + 32768, 32768L, flag);

    gemm_bt128<<<dim3(2048 / 128, M / 128), blk, 0, stream>>>(xb, wqb, qpreb, M, 2048, 2048, 3, flag);
    gemm_bt128<<<dim3(2048 / 128, M / 128), blk, 0, stream>>>(xb, wkb, kpreb, M, 2048, 2048, 3, flag);
    gemm_bt128<<<dim3(4096 / 128, M / 128), blk, 0, stream>>>(xb, wvb, vpreb, M, 4096, 2048, 3, flag);
    ab_gemm<<<dim3(64), blk, 0, stream>>>(xb, wab, alphaT, betaT);

    cvt_bf16<<<dim3(4096), blk, 0, stream>>>(Wo, wob, 8388608L, flag);  // after all xb readers

    conv_silu_norm<<<dim3(M), blk, 0, stream>>>(qpreb, qcW, qcB, qn, flag);
    conv_silu_norm<<<dim3(M), blk, 0, stream>>>(kpreb, kcW, kcB, kn, flag);
    conv_silu_v<<<dim3(M), blk, 0, stream>>>(vpreb, vcW, vcB, vn, flag);

    recurrence_kernel<<<dim3(256), blk, 0, stream>>>(qn, kn, vn, alphaT, betaT, st0,
                                                     outs, d_out, flag);

    gemm_bt128<<<dim3(2048 / 128, M / 128), blk, 0, stream>>>(outs, wob, d_out, M, 2048, 4096, 2, flag);
}